// Round 1
// baseline (1126.055 us; speedup 1.0000x reference)
//
#include <hip/hip_runtime.h>

#define DEV __device__ __forceinline__

typedef __attribute__((ext_vector_type(8))) short bfx8;
typedef __attribute__((ext_vector_type(4))) float fx4;

DEV short f2bf(float f) {
  unsigned u = __float_as_uint(f);
  u += 0x7fffu + ((u >> 16) & 1u);
  return (short)(u >> 16);
}
DEV float bf2f(short s) {
  return __uint_as_float(((unsigned)(unsigned short)s) << 16);
}
DEV float gelu_f(float x) { return 0.5f * x * (1.0f + erff(x * 0.70710678118654752f)); }

#define MFMA16(acc, a, b) (acc) = __builtin_amdgcn_mfma_f32_16x16x32_bf16((a), (b), (acc), 0, 0, 0)

// ---------------- conversions ----------------
struct CvtSeg { const float* src; short* dst; int n; };
struct CvtArgs { CvtSeg s[7]; };

__global__ __launch_bounds__(256) void cvt_multi(CvtArgs a) {
  CvtSeg s = a.s[blockIdx.y];
  int i = ((int)blockIdx.x * 256 + (int)threadIdx.x) * 8;
  if (i >= s.n) return;
  bfx8 o;
  #pragma unroll
  for (int j = 0; j < 8; ++j) o[j] = f2bf(s.src[i + j]);
  *(bfx8*)(s.dst + i) = o;
}

// conv2_w (768,256,3,3) -> W2t [tap][o][c]
__global__ __launch_bounds__(256) void cvt_conv2w(const float* src, short* dst) {
  long idx = ((long)blockIdx.x * 256 + threadIdx.x) * 8;
  if (idx >= 9L * 768 * 256) return;
  int tap = (int)(idx / (768 * 256));
  int rem = (int)(idx % (768 * 256));
  int o = rem / 256;
  int c0 = rem % 256;
  bfx8 v;
  #pragma unroll
  for (int j = 0; j < 8; ++j) v[j] = f2bf(src[(long)o * 2304 + (long)(c0 + j) * 9 + tap]);
  *(bfx8*)(dst + idx) = v;
}

// fm [8][256][4096] f32 -> fmT [8][4096][256] bf16
__global__ __launch_bounds__(256) void transpose_fm(const float* fm, short* fmT) {
  __shared__ float tile[64][65];
  int p0 = blockIdx.x * 64, c0 = blockIdx.y * 64, b = blockIdx.z;
  int tp = threadIdx.x & 63, tr = threadIdx.x >> 6;
  const float* src = fm + ((long)b * 256 + c0) * 4096 + p0;
  #pragma unroll
  for (int i = 0; i < 16; ++i) {
    int c = tr + i * 4;
    tile[c][tp] = src[(long)c * 4096 + tp];
  }
  __syncthreads();
  short* dst = fmT + ((long)b * 4096 + p0) * 256 + c0;
  #pragma unroll
  for (int i = 0; i < 16; ++i) {
    int pp = tr + i * 4;
    dst[(long)pp * 256 + tp] = f2bf(tile[tp][pp]);
  }
}

// ---------------- generic 64x64 MFMA GEMM: OUT[m][n] = act(sum_k A[m][k]*B[n][k] + biases) ----------------
struct GemmP {
  const short* A; const short* B; void* O;
  const float* biasN; const float* biasM; const float* rowbias;
  long lda, ldb, ldo, sA, sB, sO;
  int M, N, K, outF32, act;
};

__global__ __launch_bounds__(256) void gemm64(GemmP g) {
  const int lane = threadIdx.x & 63, wv = threadIdx.x >> 6;
  const int wm = wv >> 1, wn = wv & 1;
  const int lg = lane >> 4, li = lane & 15;
  const int m0 = blockIdx.y * 64, n0 = blockIdx.x * 64, z = blockIdx.z;
  const short* A = g.A + (long)z * g.sA;
  const short* B = g.B + (long)z * g.sB;
  const short* pA0 = A + (long)(m0 + 32 * wm + li) * g.lda + 8 * lg;
  const short* pA1 = pA0 + 16 * g.lda;
  const short* pB0 = B + (long)(n0 + 32 * wn + li) * g.ldb + 8 * lg;
  const short* pB1 = pB0 + 16 * g.ldb;
  fx4 acc[2][2] = {};
  for (int kc = 0; kc < g.K; kc += 32) {
    bfx8 a0 = *(const bfx8*)(pA0 + kc);
    bfx8 a1 = *(const bfx8*)(pA1 + kc);
    bfx8 b0 = *(const bfx8*)(pB0 + kc);
    bfx8 b1 = *(const bfx8*)(pB1 + kc);
    MFMA16(acc[0][0], a0, b0);
    MFMA16(acc[0][1], a0, b1);
    MFMA16(acc[1][0], a1, b0);
    MFMA16(acc[1][1], a1, b1);
  }
  #pragma unroll
  for (int mi = 0; mi < 2; ++mi)
    #pragma unroll
    for (int ni = 0; ni < 2; ++ni) {
      int col = n0 + 32 * wn + 16 * ni + li;
      int rowb = m0 + 32 * wm + 16 * mi + 4 * lg;
      float bn = g.biasN ? g.biasN[col] : 0.0f;
      #pragma unroll
      for (int r = 0; r < 4; ++r) {
        int row = rowb + r;
        float v = acc[mi][ni][r] + bn;
        if (g.biasM) v += g.biasM[row];
        if (g.rowbias) v += g.rowbias[(long)(row >> 6) * g.N + col];
        if (g.act == 1) v = gelu_f(v);
        long oidx = (long)z * g.sO + (long)row * g.ldo + col;
        if (g.outF32) ((float*)g.O)[oidx] = v;
        else ((short*)g.O)[oidx] = f2bf(v);
      }
    }
}

// ---------------- conv2 3x3 implicit GEMM + GN stats ----------------
__global__ __launch_bounds__(256) void conv2k(const short* xT, const short* W2t,
                                              const float* b2, short* qkv, float* stats) {
  const int lane = threadIdx.x & 63, wv = threadIdx.x >> 6;
  const int wm = wv >> 1, wn = wv & 1;
  const int lg = lane >> 4, li = lane & 15;
  const int ot = blockIdx.x, y = blockIdx.y, b = blockIdx.z;
  fx4 acc[2][2] = {};
  const short* xbase = xT + (long)b * 4096 * 256;
  const bfx8 zero8 = {0, 0, 0, 0, 0, 0, 0, 0};
  for (int dy = 0; dy < 3; ++dy) {
    int yy = y + dy - 1;
    if (yy < 0 || yy >= 64) continue;
    const short* xrow = xbase + (long)yy * 64 * 256;
    for (int dx = 0; dx < 3; ++dx) {
      const short* wt = W2t + (long)(dy * 3 + dx) * 768 * 256 + (long)(ot * 64 + 32 * wn + li) * 256 + 8 * lg;
      int x0 = 32 * wm + li + dx - 1;
      int x1 = x0 + 16;
      bool v0 = (x0 >= 0 && x0 < 64);
      bool v1 = (x1 >= 0 && x1 < 64);
      const short* pa0 = xrow + (long)x0 * 256 + 8 * lg;
      const short* pa1 = xrow + (long)x1 * 256 + 8 * lg;
      for (int kc = 0; kc < 256; kc += 32) {
        bfx8 a0 = v0 ? *(const bfx8*)(pa0 + kc) : zero8;
        bfx8 a1 = v1 ? *(const bfx8*)(pa1 + kc) : zero8;
        bfx8 b0 = *(const bfx8*)(wt + kc);
        bfx8 b1 = *(const bfx8*)(wt + 16 * 256 + kc);
        MFMA16(acc[0][0], a0, b0);
        MFMA16(acc[0][1], a0, b1);
        MFMA16(acc[1][0], a1, b0);
        MFMA16(acc[1][1], a1, b1);
      }
    }
  }
  float s1 = 0.0f, s2 = 0.0f;
  #pragma unroll
  for (int mi = 0; mi < 2; ++mi)
    #pragma unroll
    for (int ni = 0; ni < 2; ++ni) {
      int col = ot * 64 + 32 * wn + 16 * ni + li;
      float bias = b2[col];
      long rowb = (long)b * 4096 + y * 64 + 32 * wm + 16 * mi + 4 * lg;
      #pragma unroll
      for (int r = 0; r < 4; ++r) {
        float v = acc[mi][ni][r] + bias;
        s1 += v;
        s2 += v * v;
        qkv[(rowb + r) * 768 + col] = f2bf(v);
      }
    }
  for (int off = 1; off < 64; off <<= 1) {
    s1 += __shfl_xor(s1, off);
    s2 += __shfl_xor(s2, off);
  }
  __shared__ float red[8];
  if (lane == 0) { red[wv * 2] = s1; red[wv * 2 + 1] = s2; }
  __syncthreads();
  if (threadIdx.x == 0) {
    float t1 = red[0] + red[2] + red[4] + red[6];
    float t2 = red[1] + red[3] + red[5] + red[7];
    int gidx = (b * 4 + ot / 3) * 2;
    atomicAdd(&stats[gidx], t1);
    atomicAdd(&stats[gidx + 1], t2);
  }
}

__global__ void gn_fin(const float* stats, float* mufs) {
  int i = threadIdx.x;
  if (i >= 32) return;
  float n = 192.0f * 4096.0f;
  float mu = stats[i * 2] / n;
  float var = stats[i * 2 + 1] / n - mu * mu;
  mufs[i * 2] = mu;
  mufs[i * 2 + 1] = rsqrtf(var + 1e-5f);
}

__global__ __launch_bounds__(256) void gn_norm(short* qkv, const float* mufs,
                                               const float* gnw, const float* gnb) {
  long base = ((long)blockIdx.x * 256 + threadIdx.x) * 8;
  int o = (int)(base % 768);
  int bg = (int)(base / (4096L * 768)) * 4 + o / 192;
  float mu = mufs[bg * 2], rs = mufs[bg * 2 + 1];
  bfx8 v = *(bfx8*)(qkv + base);
  bfx8 w;
  #pragma unroll
  for (int j = 0; j < 8; ++j) {
    float f = bf2f(v[j]);
    f = (f - mu) * rs * gnw[o + j] + gnb[o + j];
    w[j] = f2bf(f);
  }
  *(bfx8*)(qkv + base) = w;
}

// ---------------- local window attention: 1 block per (b,window), 1 head per wave ----------------
__global__ __launch_bounds__(256) void attn_local(const short* qh, const short* kh,
                                                  const short* vhT, short* oat) {
  __shared__ short Pl[4 * 64 * 72];
  const int lane = threadIdx.x & 63, h = threadIdx.x >> 6;
  const int lg = lane >> 4, li = lane & 15;
  const int bw = blockIdx.x;
  const int b = bw >> 6, wY = bw & 63;
  const long p0 = (long)bw * 64;

  bfx8 qf[4][2], kf[4][2];
  #pragma unroll
  for (int mi = 0; mi < 4; ++mi)
    #pragma unroll
    for (int ks = 0; ks < 2; ++ks) {
      qf[mi][ks] = *(const bfx8*)(qh + (p0 + 16 * mi + li) * 256 + h * 64 + 32 * ks + 8 * lg);
      kf[mi][ks] = *(const bfx8*)(kh + (p0 + 16 * mi + li) * 256 + h * 64 + 32 * ks + 8 * lg);
    }
  fx4 s[4][4] = {};
  #pragma unroll
  for (int mi = 0; mi < 4; ++mi)
    #pragma unroll
    for (int ni = 0; ni < 4; ++ni) {
      MFMA16(s[mi][ni], qf[mi][0], kf[ni][0]);
      MFMA16(s[mi][ni], qf[mi][1], kf[ni][1]);
    }
  #pragma unroll
  for (int mi = 0; mi < 4; ++mi)
    #pragma unroll
    for (int ni = 0; ni < 4; ++ni) s[mi][ni] *= 0.125f;

  #pragma unroll
  for (int mi = 0; mi < 4; ++mi)
    #pragma unroll
    for (int r = 0; r < 4; ++r) {
      float mx = fmaxf(fmaxf(s[mi][0][r], s[mi][1][r]), fmaxf(s[mi][2][r], s[mi][3][r]));
      for (int off = 1; off < 16; off <<= 1) mx = fmaxf(mx, __shfl_xor(mx, off));
      float e[4];
      float sum = 0.0f;
      #pragma unroll
      for (int ni = 0; ni < 4; ++ni) { e[ni] = expf(s[mi][ni][r] - mx); sum += e[ni]; }
      for (int off = 1; off < 16; off <<= 1) sum += __shfl_xor(sum, off);
      float inv = 1.0f / sum;
      int row = h * 64 + 16 * mi + 4 * lg + r;
      #pragma unroll
      for (int ni = 0; ni < 4; ++ni) Pl[row * 72 + 16 * ni + li] = f2bf(e[ni] * inv);
    }
  __syncthreads();

  fx4 o[4][4] = {};
  #pragma unroll
  for (int ks = 0; ks < 2; ++ks) {
    bfx8 pf[4], vf[4];
    #pragma unroll
    for (int mi = 0; mi < 4; ++mi)
      pf[mi] = *(const bfx8*)(&Pl[(h * 64 + 16 * mi + li) * 72 + 32 * ks + 8 * lg]);
    #pragma unroll
    for (int ni = 0; ni < 4; ++ni)
      vf[ni] = *(const bfx8*)(vhT + ((long)(b * 256 + h * 64 + 16 * ni + li)) * 4096 + wY * 64 + 32 * ks + 8 * lg);
    #pragma unroll
    for (int mi = 0; mi < 4; ++mi)
      #pragma unroll
      for (int ni = 0; ni < 4; ++ni) MFMA16(o[mi][ni], pf[mi], vf[ni]);
  }
  #pragma unroll
  for (int mi = 0; mi < 4; ++mi)
    #pragma unroll
    for (int ni = 0; ni < 4; ++ni)
      #pragma unroll
      for (int r = 0; r < 4; ++r)
        oat[(p0 + 16 * mi + 4 * lg + r) * 256 + h * 64 + 16 * ni + li] = f2bf(o[mi][ni][r]);
}

// ---------------- small kernels ----------------
__global__ __launch_bounds__(256) void wmean(const short* loc, short* gq) {
  int bw = blockIdx.x, d = threadIdx.x;
  float s = 0.0f;
  for (int x = 0; x < 64; ++x) s += bf2f(loc[((long)bw * 64 + x) * 256 + d]);
  gq[(long)bw * 256 + d] = f2bf(s * (1.0f / 64.0f));
}

__global__ __launch_bounds__(256) void tfmean(const short* t, short* tf) {
  int bj = blockIdx.x, d = threadIdx.x;
  int b = bj >> 2, j = bj & 3;
  float s = 0.0f;
  for (int i = 0; i < 16; ++i) s += bf2f(t[((long)(b * 64 + j * 16 + i)) * 256 + d]);
  tf[(long)bj * 256 + d] = f2bf(s * (1.0f / 16.0f));
}

__global__ __launch_bounds__(256) void attn_glob(const short* tf, const short* Wqkv,
                                                 const float* inb, const short* qhg, short* og) {
  __shared__ float kh_s[4][256];
  __shared__ float vh_s[4][256];
  int b = blockIdx.x, t = threadIdx.x;
  {
    float ak[4], av[4];
    #pragma unroll
    for (int key = 0; key < 4; ++key) { ak[key] = inb[256 + t]; av[key] = inb[512 + t]; }
    const short* wk = Wqkv + (long)(256 + t) * 256;
    const short* wvp = Wqkv + (long)(512 + t) * 256;
    const short* tfb = tf + (long)b * 4 * 256;
    for (int d = 0; d < 256; ++d) {
      float wkd = bf2f(wk[d]), wvd = bf2f(wvp[d]);
      #pragma unroll
      for (int key = 0; key < 4; ++key) {
        float x = bf2f(tfb[key * 256 + d]);
        ak[key] += wkd * x;
        av[key] += wvd * x;
      }
    }
    #pragma unroll
    for (int key = 0; key < 4; ++key) { kh_s[key][t] = ak[key]; vh_s[key][t] = av[key]; }
  }
  __syncthreads();
  int wq = t >> 2, h = t & 3;
  const short* qrow = qhg + (long)(b * 64 + wq) * 256 + h * 64;
  float sc[4];
  #pragma unroll
  for (int key = 0; key < 4; ++key) {
    float s = 0.0f;
    for (int d = 0; d < 64; ++d) s += bf2f(qrow[d]) * kh_s[key][h * 64 + d];
    sc[key] = s * 0.125f;
  }
  float mx = fmaxf(fmaxf(sc[0], sc[1]), fmaxf(sc[2], sc[3]));
  float p[4], sum = 0.0f;
  #pragma unroll
  for (int key = 0; key < 4; ++key) { p[key] = expf(sc[key] - mx); sum += p[key]; }
  float inv = 1.0f / sum;
  #pragma unroll
  for (int key = 0; key < 4; ++key) p[key] *= inv;
  short* orow = og + (long)(b * 64 + wq) * 256 + h * 64;
  for (int d = 0; d < 64; ++d) {
    float o = p[0] * vh_s[0][h * 64 + d] + p[1] * vh_s[1][h * 64 + d] +
              p[2] * vh_s[2][h * 64 + d] + p[3] * vh_s[3][h * 64 + d];
    orow[d] = f2bf(o);
  }
}

__global__ __launch_bounds__(256) void ep2k(const short* hb, const short* w2, const float* b2, float* out) {
  int pp = blockIdx.x * 16 + (threadIdx.x >> 4);
  int e = threadIdx.x & 15;
  const short* hr = hb + (long)pp * 256;
  const short* wr = w2 + (long)e * 256;
  float acc = b2[e];
  for (int k = 0; k < 256; k += 8) {
    bfx8 hv = *(const bfx8*)(hr + k);
    bfx8 wv = *(const bfx8*)(wr + k);
    #pragma unroll
    for (int j = 0; j < 8; ++j) acc += bf2f(hv[j]) * bf2f(wv[j]);
  }
  out[(long)pp * 16 + e] = 1.0f / (1.0f + expf(-acc));
}

// ---------------- host ----------------
extern "C" void kernel_launch(void* const* d_in, const int* in_sizes, int n_in,
                              void* d_out, int out_size, void* d_ws, size_t ws_size,
                              hipStream_t stream) {
  (void)in_sizes; (void)n_in; (void)out_size; (void)ws_size;
  const float* fm  = (const float*)d_in[0];
  const float* txt = (const float*)d_in[1];
  const float* w1  = (const float*)d_in[2];
  const float* b1  = (const float*)d_in[3];
  const float* w2  = (const float*)d_in[4];
  const float* b2  = (const float*)d_in[5];
  const float* gnw = (const float*)d_in[6];
  const float* gnb = (const float*)d_in[7];
  const float* inw = (const float*)d_in[8];
  const float* inb = (const float*)d_in[9];
  const float* ow  = (const float*)d_in[10];
  const float* ob  = (const float*)d_in[11];
  const float* tw  = (const float*)d_in[12];
  const float* tb  = (const float*)d_in[13];
  const float* e1w = (const float*)d_in[14];
  const float* e1b = (const float*)d_in[15];
  const float* e2w = (const float*)d_in[16];
  const float* e2b = (const float*)d_in[17];
  float* out = (float*)d_out;

  char* base = (char*)d_ws;
  size_t off = 0;
  auto alloc = [&](size_t bytes) -> char* {
    char* r = base + off;
    off = (off + bytes + 255) & ~(size_t)255;
    return r;
  };
  short* W1bf = (short*)alloc(256 * 256 * 2);
  short* W2t  = (short*)alloc((size_t)9 * 768 * 256 * 2);
  short* Wqkv = (short*)alloc(768 * 256 * 2);
  short* Wo   = (short*)alloc(256 * 256 * 2);
  short* Wtxt = (short*)alloc(256 * 512 * 2);
  short* Wep1 = (short*)alloc(256 * 512 * 2);
  short* Wep2 = (short*)alloc(16 * 256 * 2);
  short* Tbf  = (short*)alloc((size_t)8 * 64 * 512 * 2);
  short* fmT  = (short*)alloc((size_t)8 * 4096 * 256 * 2);
  short* xT   = (short*)alloc((size_t)8 * 4096 * 256 * 2);
  short* qkv  = (short*)alloc((size_t)8 * 4096 * 768 * 2);
  float* stats= (float*)alloc(64 * 4);
  float* mufs = (float*)alloc(64 * 4);
  short* qh   = (short*)alloc((size_t)8 * 4096 * 256 * 2);
  short* kh   = (short*)alloc((size_t)8 * 4096 * 256 * 2);
  short* vhT  = (short*)alloc((size_t)8 * 4096 * 256 * 2);
  short* oat  = (short*)alloc((size_t)8 * 4096 * 256 * 2);
  short* loc  = (short*)alloc((size_t)8 * 4096 * 256 * 2);
  short* gq   = (short*)alloc(512 * 256 * 2);
  short* tm   = (short*)alloc(512 * 256 * 2);
  short* tfb  = (short*)alloc(32 * 256 * 2);
  short* qhg  = (short*)alloc(512 * 256 * 2);
  short* og   = (short*)alloc(512 * 256 * 2);
  short* glb  = (short*)alloc(512 * 256 * 2);
  float* gcon = (float*)alloc(512 * 256 * 4);
  short* hbuf = (short*)alloc((size_t)8 * 4096 * 256 * 2);

  hipMemsetAsync(stats, 0, 64 * 4, stream);

  CvtArgs ca;
  ca.s[0] = {w1,  W1bf, 256 * 256};
  ca.s[1] = {inw, Wqkv, 768 * 256};
  ca.s[2] = {ow,  Wo,   256 * 256};
  ca.s[3] = {tw,  Wtxt, 256 * 512};
  ca.s[4] = {e1w, Wep1, 256 * 512};
  ca.s[5] = {e2w, Wep2, 16 * 256};
  ca.s[6] = {txt, Tbf,  8 * 64 * 512};
  cvt_multi<<<dim3(128, 7), 256, 0, stream>>>(ca);
  cvt_conv2w<<<864, 256, 0, stream>>>(w2, W2t);
  transpose_fm<<<dim3(64, 4, 8), 256, 0, stream>>>(fm, fmT);

  { // conv1 1x1 + gelu -> xT [b][p][256]
    GemmP g{};
    g.A = fmT; g.lda = 256; g.sA = 4096L * 256;
    g.B = W1bf; g.ldb = 256; g.sB = 0;
    g.O = xT; g.ldo = 256; g.sO = 4096L * 256;
    g.biasN = b1; g.M = 4096; g.N = 256; g.K = 256; g.act = 1; g.outF32 = 0;
    gemm64<<<dim3(4, 64, 8), 256, 0, stream>>>(g);
  }

  conv2k<<<dim3(12, 64, 8), 256, 0, stream>>>(xT, W2t, b2, qkv, stats);
  gn_fin<<<1, 32, 0, stream>>>(stats, mufs);
  gn_norm<<<12288, 256, 0, stream>>>(qkv, mufs, gnw, gnb);

  { // proj q
    GemmP g{};
    g.A = qkv; g.lda = 768; g.sA = 4096L * 768;
    g.B = Wqkv; g.ldb = 256; g.sB = 0;
    g.O = qh; g.ldo = 256; g.sO = 4096L * 256;
    g.biasN = inb; g.M = 4096; g.N = 256; g.K = 256;
    gemm64<<<dim3(4, 64, 8), 256, 0, stream>>>(g);
  }
  { // proj k
    GemmP g{};
    g.A = qkv; g.lda = 768; g.sA = 4096L * 768;
    g.B = Wqkv + 256 * 256; g.ldb = 256; g.sB = 0;
    g.O = kh; g.ldo = 256; g.sO = 4096L * 256;
    g.biasN = inb + 256; g.M = 4096; g.N = 256; g.K = 256;
    gemm64<<<dim3(4, 64, 8), 256, 0, stream>>>(g);
  }
  { // proj v, transposed output vhT [b][dout][p]
    GemmP g{};
    g.A = Wqkv + 512 * 256; g.lda = 256; g.sA = 0;
    g.B = qkv + 512; g.ldb = 768; g.sB = 4096L * 768;
    g.O = vhT; g.ldo = 4096; g.sO = 256L * 4096;
    g.biasM = inb + 512; g.M = 256; g.N = 4096; g.K = 256;
    gemm64<<<dim3(64, 4, 8), 256, 0, stream>>>(g);
  }

  attn_local<<<512, 256, 0, stream>>>(qh, kh, vhT, oat);

  { // out_proj -> loc
    GemmP g{};
    g.A = oat; g.lda = 256; g.B = Wo; g.ldb = 256;
    g.O = loc; g.ldo = 256; g.biasN = ob;
    g.M = 32768; g.N = 256; g.K = 256;
    gemm64<<<dim3(4, 512, 1), 256, 0, stream>>>(g);
  }

  wmean<<<512, 256, 0, stream>>>(loc, gq);

  { // text proj -> tm
    GemmP g{};
    g.A = Tbf; g.lda = 512; g.B = Wtxt; g.ldb = 512;
    g.O = tm; g.ldo = 256; g.biasN = tb;
    g.M = 512; g.N = 256; g.K = 512;
    gemm64<<<dim3(4, 8, 1), 256, 0, stream>>>(g);
  }
  tfmean<<<32, 256, 0, stream>>>(tm, tfb);

  { // global q projection
    GemmP g{};
    g.A = gq; g.lda = 256; g.B = Wqkv; g.ldb = 256;
    g.O = qhg; g.ldo = 256; g.biasN = inb;
    g.M = 512; g.N = 256; g.K = 256;
    gemm64<<<dim3(4, 8, 1), 256, 0, stream>>>(g);
  }

  attn_glob<<<8, 256, 0, stream>>>(tfb, Wqkv, inb, qhg, og);

  { // global out_proj -> glb
    GemmP g{};
    g.A = og; g.lda = 256; g.B = Wo; g.ldb = 256;
    g.O = glb; g.ldo = 256; g.biasN = ob;
    g.M = 512; g.N = 256; g.K = 256;
    gemm64<<<dim3(4, 8, 1), 256, 0, stream>>>(g);
  }
  { // gcontrib = glb @ ep1_w[:,256:].T + ep1_b  (f32)
    GemmP g{};
    g.A = glb; g.lda = 256; g.B = Wep1 + 256; g.ldb = 512;
    g.O = gcon; g.ldo = 256; g.biasN = e1b; g.outF32 = 1;
    g.M = 512; g.N = 256; g.K = 256;
    gemm64<<<dim3(4, 8, 1), 256, 0, stream>>>(g);
  }
  { // ep1: h = gelu(loc @ ep1_w[:,:256].T + gcontrib[row>>6])
    GemmP g{};
    g.A = loc; g.lda = 256; g.B = Wep1; g.ldb = 512;
    g.O = hbuf; g.ldo = 256; g.rowbias = gcon; g.act = 1;
    g.M = 32768; g.N = 256; g.K = 256;
    gemm64<<<dim3(4, 512, 1), 256, 0, stream>>>(g);
  }

  ep2k<<<2048, 256, 0, stream>>>(hbuf, Wep2, e2b, out);
}

// Round 2
// 536.678 us; speedup vs baseline: 2.0982x; 2.0982x over previous
//
#include <hip/hip_runtime.h>

#define DEV __device__ __forceinline__

typedef __attribute__((ext_vector_type(8))) short bfx8;
typedef __attribute__((ext_vector_type(4))) float fx4;

typedef __attribute__((address_space(3))) unsigned int as3_u32;
typedef const __attribute__((address_space(1))) unsigned int as1_u32c;

DEV void gl_lds16(const void* g, const void* l) {
  __builtin_amdgcn_global_load_lds((as1_u32c*)(unsigned long long)g,
                                   (as3_u32*)(unsigned long long)l, 16, 0, 0);
}

DEV short f2bf(float f) {
  unsigned u = __float_as_uint(f);
  u += 0x7fffu + ((u >> 16) & 1u);
  return (short)(u >> 16);
}
DEV float bf2f(short s) {
  return __uint_as_float(((unsigned)(unsigned short)s) << 16);
}
DEV float gelu_f(float x) { return 0.5f * x * (1.0f + erff(x * 0.70710678118654752f)); }

#define MFMA16(acc, a, b) (acc) = __builtin_amdgcn_mfma_f32_16x16x32_bf16((a), (b), (acc), 0, 0, 0)

// ---------------- conversions ----------------
struct CvtSeg { const float* src; short* dst; int n; };
struct CvtArgs { CvtSeg s[7]; };

__global__ __launch_bounds__(256) void cvt_multi(CvtArgs a) {
  CvtSeg s = a.s[blockIdx.y];
  int i = ((int)blockIdx.x * 256 + (int)threadIdx.x) * 8;
  if (i >= s.n) return;
  bfx8 o;
  #pragma unroll
  for (int j = 0; j < 8; ++j) o[j] = f2bf(s.src[i + j]);
  *(bfx8*)(s.dst + i) = o;
}

// conv2_w (768,256,3,3) -> W2t [tap][o][c]
__global__ __launch_bounds__(256) void cvt_conv2w(const float* src, short* dst) {
  long idx = ((long)blockIdx.x * 256 + threadIdx.x) * 8;
  if (idx >= 9L * 768 * 256) return;
  int tap = (int)(idx / (768 * 256));
  int rem = (int)(idx % (768 * 256));
  int o = rem / 256;
  int c0 = rem % 256;
  bfx8 v;
  #pragma unroll
  for (int j = 0; j < 8; ++j) v[j] = f2bf(src[(long)o * 2304 + (long)(c0 + j) * 9 + tap]);
  *(bfx8*)(dst + idx) = v;
}

// fm [8][256][4096] f32 -> fmT [8][4096][256] bf16
__global__ __launch_bounds__(256) void transpose_fm(const float* fm, short* fmT) {
  __shared__ float tile[64][65];
  int p0 = blockIdx.x * 64, c0 = blockIdx.y * 64, b = blockIdx.z;
  int tp = threadIdx.x & 63, tr = threadIdx.x >> 6;
  const float* src = fm + ((long)b * 256 + c0) * 4096 + p0;
  #pragma unroll
  for (int i = 0; i < 16; ++i) {
    int c = tr + i * 4;
    tile[c][tp] = src[(long)c * 4096 + tp];
  }
  __syncthreads();
  short* dst = fmT + ((long)b * 4096 + p0) * 256 + c0;
  #pragma unroll
  for (int i = 0; i < 16; ++i) {
    int pp = tr + i * 4;
    dst[(long)pp * 256 + tp] = f2bf(tile[tp][pp]);
  }
}

// ---------------- generic 64x64 MFMA GEMM: OUT[m][n] = act(sum_k A[m][k]*B[n][k] + biases) ----------------
struct GemmP {
  const short* A; const short* B; void* O;
  const float* biasN; const float* biasM; const float* rowbias;
  long lda, ldb, ldo, sA, sB, sO;
  int M, N, K, outF32, act, padHW;
};

__global__ __launch_bounds__(256) void gemm64(GemmP g) {
  const int lane = threadIdx.x & 63, wv = threadIdx.x >> 6;
  const int wm = wv >> 1, wn = wv & 1;
  const int lg = lane >> 4, li = lane & 15;
  const int m0 = blockIdx.y * 64, n0 = blockIdx.x * 64, z = blockIdx.z;
  const short* A = g.A + (long)z * g.sA;
  const short* B = g.B + (long)z * g.sB;
  const short* pA0 = A + (long)(m0 + 32 * wm + li) * g.lda + 8 * lg;
  const short* pA1 = pA0 + 16 * g.lda;
  const short* pB0 = B + (long)(n0 + 32 * wn + li) * g.ldb + 8 * lg;
  const short* pB1 = pB0 + 16 * g.ldb;
  fx4 acc[2][2] = {};
  for (int kc = 0; kc < g.K; kc += 32) {
    bfx8 a0 = *(const bfx8*)(pA0 + kc);
    bfx8 a1 = *(const bfx8*)(pA1 + kc);
    bfx8 b0 = *(const bfx8*)(pB0 + kc);
    bfx8 b1 = *(const bfx8*)(pB1 + kc);
    MFMA16(acc[0][0], a0, b0);
    MFMA16(acc[0][1], a0, b1);
    MFMA16(acc[1][0], a1, b0);
    MFMA16(acc[1][1], a1, b1);
  }
  #pragma unroll
  for (int mi = 0; mi < 2; ++mi)
    #pragma unroll
    for (int ni = 0; ni < 2; ++ni) {
      int col = n0 + 32 * wn + 16 * ni + li;
      int rowb = m0 + 32 * wm + 16 * mi + 4 * lg;
      float bn = g.biasN ? g.biasN[col] : 0.0f;
      #pragma unroll
      for (int r = 0; r < 4; ++r) {
        int row = rowb + r;
        float v = acc[mi][ni][r] + bn;
        if (g.biasM) v += g.biasM[row];
        if (g.rowbias) v += g.rowbias[(long)(row >> 6) * g.N + col];
        if (g.act == 1) v = gelu_f(v);
        long orow = row;
        if (g.padHW) orow = (long)((row >> 6) + 1) * 66 + (row & 63) + 1;
        long oidx = (long)z * g.sO + orow * g.ldo + col;
        if (g.outF32) ((float*)g.O)[oidx] = v;
        else ((short*)g.O)[oidx] = f2bf(v);
      }
    }
}

// ---------------- conv2 3x3 implicit GEMM (m97 structure) + fused GN stats ----------------
// xP: [8][66][66][256] bf16, zero border. W2t: [tap][768][256]. qkv: [8][4096][768].
__global__ __launch_bounds__(256) void conv2g(const short* xP, const short* W2t,
                                              const float* b2, short* qkv, float* stats) {
  __shared__ short As[128 * 32];
  __shared__ short Bs[128 * 32];
  __shared__ float red[4][4];
  const int lane = threadIdx.x & 63, wv = threadIdx.x >> 6;
  const int wm = wv >> 1, wn = wv & 1;
  const int lg = lane >> 4, li = lane & 15;
  const int n0 = blockIdx.x * 128;
  const int by = blockIdx.y;
  const int b = by >> 5, ypair = by & 31;
  const short* xPb = xP + (long)b * 66 * 66 * 256;

  // staging lane geometry: wave wv stages LDS rows [wv*16 + j*64, +16)
  const int srow = wv * 16 + (lane >> 2);
  const int scol = (lane & 3) * 8;
  long baseA[2], baseB[2];
  #pragma unroll
  for (int j = 0; j < 2; ++j) {
    int r = j * 64 + srow;
    int yy = 2 * ypair + (r >> 6);
    int x = r & 63;
    baseA[j] = ((long)yy * 66 + x) * 256 + scol;
    baseB[j] = (long)(n0 + r) * 256 + scol;
  }
  short* ldsA = As + wv * 512;
  short* ldsB = Bs + wv * 512;
  const short* aRd = As + (wm * 64 + li) * 32 + lg * 8;
  const short* bRd = Bs + (wn * 64 + li) * 32 + lg * 8;

  fx4 acc[4][4] = {};
  for (int ks = 0; ks < 72; ++ks) {
    int tap = ks >> 3;
    int c0 = (ks & 7) * 32;
    int dy = tap / 3, dx = tap - dy * 3;
    long aoff = (long)(dy * 66 + dx) * 256 + c0;
    long boff = (long)tap * (768 * 256) + c0;
    gl_lds16(xPb + baseA[0] + aoff, ldsA);
    gl_lds16(xPb + baseA[1] + aoff, ldsA + 2048);
    gl_lds16(W2t + baseB[0] + boff, ldsB);
    gl_lds16(W2t + baseB[1] + boff, ldsB + 2048);
    __syncthreads();
    bfx8 af[4], bf[4];
    #pragma unroll
    for (int mi = 0; mi < 4; ++mi) af[mi] = *(const bfx8*)(aRd + mi * 16 * 32);
    #pragma unroll
    for (int ni = 0; ni < 4; ++ni) bf[ni] = *(const bfx8*)(bRd + ni * 16 * 32);
    #pragma unroll
    for (int mi = 0; mi < 4; ++mi)
      #pragma unroll
      for (int ni = 0; ni < 4; ++ni)
        MFMA16(acc[mi][ni], af[mi], bf[ni]);
    __syncthreads();
  }

  // epilogue: bias, GN partial stats (group = col/192), store bf16
  const int g0 = n0 / 192;
  const int bnd = (g0 + 1) * 192;
  float sA = 0.0f, s2A = 0.0f, sB = 0.0f, s2B = 0.0f;
  const long prow0 = (long)b * 4096 + (long)ypair * 128 + wm * 64 + 4 * lg;
  #pragma unroll
  for (int ni = 0; ni < 4; ++ni) {
    int col = n0 + wn * 64 + ni * 16 + li;
    float bias = b2[col];
    bool inA = (col < bnd);
    #pragma unroll
    for (int mi = 0; mi < 4; ++mi) {
      long rb = prow0 + mi * 16;
      #pragma unroll
      for (int r = 0; r < 4; ++r) {
        float v = acc[mi][ni][r] + bias;
        if (inA) { sA += v; s2A += v * v; } else { sB += v; s2B += v * v; }
        qkv[(rb + r) * 768 + col] = f2bf(v);
      }
    }
  }
  #pragma unroll
  for (int off = 1; off < 64; off <<= 1) {
    sA += __shfl_xor(sA, off);  s2A += __shfl_xor(s2A, off);
    sB += __shfl_xor(sB, off);  s2B += __shfl_xor(s2B, off);
  }
  if (lane == 0) { red[wv][0] = sA; red[wv][1] = s2A; red[wv][2] = sB; red[wv][3] = s2B; }
  __syncthreads();
  if (threadIdx.x == 0) {
    float a1 = red[0][0] + red[1][0] + red[2][0] + red[3][0];
    float a2 = red[0][1] + red[1][1] + red[2][1] + red[3][1];
    atomicAdd(&stats[(b * 4 + g0) * 2], a1);
    atomicAdd(&stats[(b * 4 + g0) * 2 + 1], a2);
    if (bnd < n0 + 128) {
      float b1s = red[0][2] + red[1][2] + red[2][2] + red[3][2];
      float b2s = red[0][3] + red[1][3] + red[2][3] + red[3][3];
      atomicAdd(&stats[(b * 4 + g0 + 1) * 2], b1s);
      atomicAdd(&stats[(b * 4 + g0 + 1) * 2 + 1], b2s);
    }
  }
}

__global__ void gn_fin(const float* stats, float* mufs) {
  int i = threadIdx.x;
  if (i >= 32) return;
  float n = 192.0f * 4096.0f;
  float mu = stats[i * 2] / n;
  float var = stats[i * 2 + 1] / n - mu * mu;
  mufs[i * 2] = mu;
  mufs[i * 2 + 1] = rsqrtf(var + 1e-5f);
}

__global__ __launch_bounds__(256) void gn_norm(short* qkv, const float* mufs,
                                               const float* gnw, const float* gnb) {
  long base = ((long)blockIdx.x * 256 + threadIdx.x) * 8;
  int o = (int)(base % 768);
  int bg = (int)(base / (4096L * 768)) * 4 + o / 192;
  float mu = mufs[bg * 2], rs = mufs[bg * 2 + 1];
  bfx8 v = *(bfx8*)(qkv + base);
  bfx8 w;
  #pragma unroll
  for (int j = 0; j < 8; ++j) {
    float f = bf2f(v[j]);
    f = (f - mu) * rs * gnw[o + j] + gnb[o + j];
    w[j] = f2bf(f);
  }
  *(bfx8*)(qkv + base) = w;
}

// ---------------- local window attention: 1 block per (b,window), 1 head per wave ----------------
__global__ __launch_bounds__(256) void attn_local(const short* qh, const short* kh,
                                                  const short* vhT, short* oat) {
  __shared__ short Pl[4 * 64 * 72];
  const int lane = threadIdx.x & 63, h = threadIdx.x >> 6;
  const int lg = lane >> 4, li = lane & 15;
  const int bw = blockIdx.x;
  const int b = bw >> 6, wY = bw & 63;
  const long p0 = (long)bw * 64;

  bfx8 qf[4][2], kf[4][2];
  #pragma unroll
  for (int mi = 0; mi < 4; ++mi)
    #pragma unroll
    for (int ks = 0; ks < 2; ++ks) {
      qf[mi][ks] = *(const bfx8*)(qh + (p0 + 16 * mi + li) * 256 + h * 64 + 32 * ks + 8 * lg);
      kf[mi][ks] = *(const bfx8*)(kh + (p0 + 16 * mi + li) * 256 + h * 64 + 32 * ks + 8 * lg);
    }
  fx4 s[4][4] = {};
  #pragma unroll
  for (int mi = 0; mi < 4; ++mi)
    #pragma unroll
    for (int ni = 0; ni < 4; ++ni) {
      MFMA16(s[mi][ni], qf[mi][0], kf[ni][0]);
      MFMA16(s[mi][ni], qf[mi][1], kf[ni][1]);
    }
  #pragma unroll
  for (int mi = 0; mi < 4; ++mi)
    #pragma unroll
    for (int ni = 0; ni < 4; ++ni) s[mi][ni] *= 0.125f;

  #pragma unroll
  for (int mi = 0; mi < 4; ++mi)
    #pragma unroll
    for (int r = 0; r < 4; ++r) {
      float mx = fmaxf(fmaxf(s[mi][0][r], s[mi][1][r]), fmaxf(s[mi][2][r], s[mi][3][r]));
      for (int off = 1; off < 16; off <<= 1) mx = fmaxf(mx, __shfl_xor(mx, off));
      float e[4];
      float sum = 0.0f;
      #pragma unroll
      for (int ni = 0; ni < 4; ++ni) { e[ni] = expf(s[mi][ni][r] - mx); sum += e[ni]; }
      for (int off = 1; off < 16; off <<= 1) sum += __shfl_xor(sum, off);
      float inv = 1.0f / sum;
      int row = h * 64 + 16 * mi + 4 * lg + r;
      #pragma unroll
      for (int ni = 0; ni < 4; ++ni) Pl[row * 72 + 16 * ni + li] = f2bf(e[ni] * inv);
    }
  __syncthreads();

  fx4 o[4][4] = {};
  #pragma unroll
  for (int ks = 0; ks < 2; ++ks) {
    bfx8 pf[4], vf[4];
    #pragma unroll
    for (int mi = 0; mi < 4; ++mi)
      pf[mi] = *(const bfx8*)(&Pl[(h * 64 + 16 * mi + li) * 72 + 32 * ks + 8 * lg]);
    #pragma unroll
    for (int ni = 0; ni < 4; ++ni)
      vf[ni] = *(const bfx8*)(vhT + ((long)(b * 256 + h * 64 + 16 * ni + li)) * 4096 + wY * 64 + 32 * ks + 8 * lg);
    #pragma unroll
    for (int mi = 0; mi < 4; ++mi)
      #pragma unroll
      for (int ni = 0; ni < 4; ++ni) MFMA16(o[mi][ni], pf[mi], vf[ni]);
  }
  #pragma unroll
  for (int mi = 0; mi < 4; ++mi)
    #pragma unroll
    for (int ni = 0; ni < 4; ++ni)
      #pragma unroll
      for (int r = 0; r < 4; ++r)
        oat[(p0 + 16 * mi + 4 * lg + r) * 256 + h * 64 + 16 * ni + li] = f2bf(o[mi][ni][r]);
}

// ---------------- small kernels ----------------
__global__ __launch_bounds__(256) void wmean(const short* loc, short* gq) {
  int bw = blockIdx.x, d = threadIdx.x;
  float s = 0.0f;
  for (int x = 0; x < 64; ++x) s += bf2f(loc[((long)bw * 64 + x) * 256 + d]);
  gq[(long)bw * 256 + d] = f2bf(s * (1.0f / 64.0f));
}

__global__ __launch_bounds__(256) void tfmean(const short* t, short* tf) {
  int bj = blockIdx.x, d = threadIdx.x;
  int b = bj >> 2, j = bj & 3;
  float s = 0.0f;
  for (int i = 0; i < 16; ++i) s += bf2f(t[((long)(b * 64 + j * 16 + i)) * 256 + d]);
  tf[(long)bj * 256 + d] = f2bf(s * (1.0f / 16.0f));
}

__global__ __launch_bounds__(256) void attn_glob(const short* tf, const short* Wqkv,
                                                 const float* inb, const short* qhg, short* og) {
  __shared__ float kh_s[4][256];
  __shared__ float vh_s[4][256];
  int b = blockIdx.x, t = threadIdx.x;
  {
    float ak[4], av[4];
    #pragma unroll
    for (int key = 0; key < 4; ++key) { ak[key] = inb[256 + t]; av[key] = inb[512 + t]; }
    const short* wk = Wqkv + (long)(256 + t) * 256;
    const short* wvp = Wqkv + (long)(512 + t) * 256;
    const short* tfb = tf + (long)b * 4 * 256;
    for (int d = 0; d < 256; ++d) {
      float wkd = bf2f(wk[d]), wvd = bf2f(wvp[d]);
      #pragma unroll
      for (int key = 0; key < 4; ++key) {
        float x = bf2f(tfb[key * 256 + d]);
        ak[key] += wkd * x;
        av[key] += wvd * x;
      }
    }
    #pragma unroll
    for (int key = 0; key < 4; ++key) { kh_s[key][t] = ak[key]; vh_s[key][t] = av[key]; }
  }
  __syncthreads();
  int wq = t >> 2, h = t & 3;
  const short* qrow = qhg + (long)(b * 64 + wq) * 256 + h * 64;
  float sc[4];
  #pragma unroll
  for (int key = 0; key < 4; ++key) {
    float s = 0.0f;
    for (int d = 0; d < 64; ++d) s += bf2f(qrow[d]) * kh_s[key][h * 64 + d];
    sc[key] = s * 0.125f;
  }
  float mx = fmaxf(fmaxf(sc[0], sc[1]), fmaxf(sc[2], sc[3]));
  float p[4], sum = 0.0f;
  #pragma unroll
  for (int key = 0; key < 4; ++key) { p[key] = expf(sc[key] - mx); sum += p[key]; }
  float inv = 1.0f / sum;
  #pragma unroll
  for (int key = 0; key < 4; ++key) p[key] *= inv;
  short* orow = og + (long)(b * 64 + wq) * 256 + h * 64;
  for (int d = 0; d < 64; ++d) {
    float o = p[0] * vh_s[0][h * 64 + d] + p[1] * vh_s[1][h * 64 + d] +
              p[2] * vh_s[2][h * 64 + d] + p[3] * vh_s[3][h * 64 + d];
    orow[d] = f2bf(o);
  }
}

__global__ __launch_bounds__(256) void ep2k(const short* hb, const short* w2, const float* b2, float* out) {
  int pp = blockIdx.x * 16 + (threadIdx.x >> 4);
  int e = threadIdx.x & 15;
  const short* hr = hb + (long)pp * 256;
  const short* wr = w2 + (long)e * 256;
  float acc = b2[e];
  for (int k = 0; k < 256; k += 8) {
    bfx8 hv = *(const bfx8*)(hr + k);
    bfx8 wv = *(const bfx8*)(wr + k);
    #pragma unroll
    for (int j = 0; j < 8; ++j) acc += bf2f(hv[j]) * bf2f(wv[j]);
  }
  out[(long)pp * 16 + e] = 1.0f / (1.0f + expf(-acc));
}

// ---------------- host ----------------
extern "C" void kernel_launch(void* const* d_in, const int* in_sizes, int n_in,
                              void* d_out, int out_size, void* d_ws, size_t ws_size,
                              hipStream_t stream) {
  (void)in_sizes; (void)n_in; (void)out_size; (void)ws_size;
  const float* fm  = (const float*)d_in[0];
  const float* txt = (const float*)d_in[1];
  const float* w1  = (const float*)d_in[2];
  const float* b1  = (const float*)d_in[3];
  const float* w2  = (const float*)d_in[4];
  const float* b2  = (const float*)d_in[5];
  const float* gnw = (const float*)d_in[6];
  const float* gnb = (const float*)d_in[7];
  const float* inw = (const float*)d_in[8];
  const float* inb = (const float*)d_in[9];
  const float* ow  = (const float*)d_in[10];
  const float* ob  = (const float*)d_in[11];
  const float* tw  = (const float*)d_in[12];
  const float* tb  = (const float*)d_in[13];
  const float* e1w = (const float*)d_in[14];
  const float* e1b = (const float*)d_in[15];
  const float* e2w = (const float*)d_in[16];
  const float* e2b = (const float*)d_in[17];
  float* out = (float*)d_out;

  char* base = (char*)d_ws;
  size_t off = 0;
  auto alloc = [&](size_t bytes) -> char* {
    char* r = base + off;
    off = (off + bytes + 255) & ~(size_t)255;
    return r;
  };
  short* W1bf = (short*)alloc(256 * 256 * 2);
  short* W2t  = (short*)alloc((size_t)9 * 768 * 256 * 2);
  short* Wqkv = (short*)alloc(768 * 256 * 2);
  short* Wo   = (short*)alloc(256 * 256 * 2);
  short* Wtxt = (short*)alloc(256 * 512 * 2);
  short* Wep1 = (short*)alloc(256 * 512 * 2);
  short* Wep2 = (short*)alloc(16 * 256 * 2);
  short* Tbf  = (short*)alloc((size_t)8 * 64 * 512 * 2);
  short* fmT  = (short*)alloc((size_t)8 * 4096 * 256 * 2);
  short* xP   = (short*)alloc((size_t)8 * 66 * 66 * 256 * 2);
  short* qkv  = (short*)alloc((size_t)8 * 4096 * 768 * 2);
  float* stats= (float*)alloc(64 * 4);
  float* mufs = (float*)alloc(64 * 4);
  short* qh   = (short*)alloc((size_t)8 * 4096 * 256 * 2);
  short* kh   = (short*)alloc((size_t)8 * 4096 * 256 * 2);
  short* vhT  = (short*)alloc((size_t)8 * 4096 * 256 * 2);
  short* oat  = (short*)alloc((size_t)8 * 4096 * 256 * 2);
  short* loc  = (short*)alloc((size_t)8 * 4096 * 256 * 2);
  short* gq   = (short*)alloc(512 * 256 * 2);
  short* tm   = (short*)alloc(512 * 256 * 2);
  short* tfb  = (short*)alloc(32 * 256 * 2);
  short* qhg  = (short*)alloc(512 * 256 * 2);
  short* og   = (short*)alloc(512 * 256 * 2);
  short* glb  = (short*)alloc(512 * 256 * 2);
  float* gcon = (float*)alloc(512 * 256 * 4);
  short* hbuf = (short*)alloc((size_t)8 * 4096 * 256 * 2);

  hipMemsetAsync(stats, 0, 64 * 4, stream);
  hipMemsetAsync(xP, 0, (size_t)8 * 66 * 66 * 256 * 2, stream);

  CvtArgs ca;
  ca.s[0] = {w1,  W1bf, 256 * 256};
  ca.s[1] = {inw, Wqkv, 768 * 256};
  ca.s[2] = {ow,  Wo,   256 * 256};
  ca.s[3] = {tw,  Wtxt, 256 * 512};
  ca.s[4] = {e1w, Wep1, 256 * 512};
  ca.s[5] = {e2w, Wep2, 16 * 256};
  ca.s[6] = {txt, Tbf,  8 * 64 * 512};
  cvt_multi<<<dim3(128, 7), 256, 0, stream>>>(ca);
  cvt_conv2w<<<864, 256, 0, stream>>>(w2, W2t);
  transpose_fm<<<dim3(64, 4, 8), 256, 0, stream>>>(fm, fmT);

  { // conv1 1x1 + gelu -> xP (padded [66][66] layout)
    GemmP g{};
    g.A = fmT; g.lda = 256; g.sA = 4096L * 256;
    g.B = W1bf; g.ldb = 256; g.sB = 0;
    g.O = xP; g.ldo = 256; g.sO = 66L * 66 * 256;
    g.biasN = b1; g.M = 4096; g.N = 256; g.K = 256; g.act = 1; g.outF32 = 0; g.padHW = 1;
    gemm64<<<dim3(4, 64, 8), 256, 0, stream>>>(g);
  }

  conv2g<<<dim3(6, 256), 256, 0, stream>>>(xP, W2t, b2, qkv, stats);
  gn_fin<<<1, 32, 0, stream>>>(stats, mufs);
  gn_norm<<<12288, 256, 0, stream>>>(qkv, mufs, gnw, gnb);

  { // proj q
    GemmP g{};
    g.A = qkv; g.lda = 768; g.sA = 4096L * 768;
    g.B = Wqkv; g.ldb = 256; g.sB = 0;
    g.O = qh; g.ldo = 256; g.sO = 4096L * 256;
    g.biasN = inb; g.M = 4096; g.N = 256; g.K = 256;
    gemm64<<<dim3(4, 64, 8), 256, 0, stream>>>(g);
  }
  { // proj k
    GemmP g{};
    g.A = qkv; g.lda = 768; g.sA = 4096L * 768;
    g.B = Wqkv + 256 * 256; g.ldb = 256; g.sB = 0;
    g.O = kh; g.ldo = 256; g.sO = 4096L * 256;
    g.biasN = inb + 256; g.M = 4096; g.N = 256; g.K = 256;
    gemm64<<<dim3(4, 64, 8), 256, 0, stream>>>(g);
  }
  { // proj v, transposed output vhT [b][dout][p]
    GemmP g{};
    g.A = Wqkv + 512 * 256; g.lda = 256; g.sA = 0;
    g.B = qkv + 512; g.ldb = 768; g.sB = 4096L * 768;
    g.O = vhT; g.ldo = 4096; g.sO = 256L * 4096;
    g.biasM = inb + 512; g.M = 256; g.N = 4096; g.K = 256;
    gemm64<<<dim3(64, 4, 8), 256, 0, stream>>>(g);
  }

  attn_local<<<512, 256, 0, stream>>>(qh, kh, vhT, oat);

  { // out_proj -> loc
    GemmP g{};
    g.A = oat; g.lda = 256; g.B = Wo; g.ldb = 256;
    g.O = loc; g.ldo = 256; g.biasN = ob;
    g.M = 32768; g.N = 256; g.K = 256;
    gemm64<<<dim3(4, 512, 1), 256, 0, stream>>>(g);
  }

  wmean<<<512, 256, 0, stream>>>(loc, gq);

  { // text proj -> tm
    GemmP g{};
    g.A = Tbf; g.lda = 512; g.B = Wtxt; g.ldb = 512;
    g.O = tm; g.ldo = 256; g.biasN = tb;
    g.M = 512; g.N = 256; g.K = 512;
    gemm64<<<dim3(4, 8, 1), 256, 0, stream>>>(g);
  }
  tfmean<<<32, 256, 0, stream>>>(tm, tfb);

  { // global q projection
    GemmP g{};
    g.A = gq; g.lda = 256; g.B = Wqkv; g.ldb = 256;
    g.O = qhg; g.ldo = 256; g.biasN = inb;
    g.M = 512; g.N = 256; g.K = 256;
    gemm64<<<dim3(4, 8, 1), 256, 0, stream>>>(g);
  }

  attn_glob<<<8, 256, 0, stream>>>(tfb, Wqkv, inb, qhg, og);

  { // global out_proj -> glb
    GemmP g{};
    g.A = og; g.lda = 256; g.B = Wo; g.ldb = 256;
    g.O = glb; g.ldo = 256; g.biasN = ob;
    g.M = 512; g.N = 256; g.K = 256;
    gemm64<<<dim3(4, 8, 1), 256, 0, stream>>>(g);
  }
  { // gcontrib = glb @ ep1_w[:,256:].T + ep1_b  (f32)
    GemmP g{};
    g.A = glb; g.lda = 256; g.B = Wep1 + 256; g.ldb = 512;
    g.O = gcon; g.ldo = 256; g.biasN = e1b; g.outF32 = 1;
    g.M = 512; g.N = 256; g.K = 256;
    gemm64<<<dim3(4, 8, 1), 256, 0, stream>>>(g);
  }
  { // ep1: h = gelu(loc @ ep1_w[:,:256].T + gcontrib[row>>6])
    GemmP g{};
    g.A = loc; g.lda = 256; g.B = Wep1; g.ldb = 512;
    g.O = hbuf; g.ldo = 256; g.rowbias = gcon; g.act = 1;
    g.M = 32768; g.N = 256; g.K = 256;
    gemm64<<<dim3(4, 512, 1), 256, 0, stream>>>(g);
  }

  ep2k<<<2048, 256, 0, stream>>>(hbuf, Wep2, e2b, out);
}

// Round 3
// 462.128 us; speedup vs baseline: 2.4367x; 1.1613x over previous
//
#include <hip/hip_runtime.h>

#define DEV __device__ __forceinline__

typedef __attribute__((ext_vector_type(8))) short bfx8;
typedef __attribute__((ext_vector_type(4))) float fx4;

typedef __attribute__((address_space(3))) unsigned int as3_u32;
typedef const __attribute__((address_space(1))) unsigned int as1_u32c;

DEV void gl_lds16(const void* g, const void* l) {
  __builtin_amdgcn_global_load_lds((as1_u32c*)(unsigned long long)g,
                                   (as3_u32*)(unsigned long long)l, 16, 0, 0);
}

DEV short f2bf(float f) {
  unsigned u = __float_as_uint(f);
  u += 0x7fffu + ((u >> 16) & 1u);
  return (short)(u >> 16);
}
DEV float bf2f(short s) {
  return __uint_as_float(((unsigned)(unsigned short)s) << 16);
}
DEV float gelu_f(float x) { return 0.5f * x * (1.0f + erff(x * 0.70710678118654752f)); }

#define MFMA16(acc, a, b) (acc) = __builtin_amdgcn_mfma_f32_16x16x32_bf16((a), (b), (acc), 0, 0, 0)

// ---------------- conversions ----------------
struct CvtSeg { const float* src; short* dst; int n; };
struct CvtArgs { CvtSeg s[7]; };

__global__ __launch_bounds__(256) void cvt_multi(CvtArgs a) {
  CvtSeg s = a.s[blockIdx.y];
  int i = ((int)blockIdx.x * 256 + (int)threadIdx.x) * 8;
  if (i >= s.n) return;
  bfx8 o;
  #pragma unroll
  for (int j = 0; j < 8; ++j) o[j] = f2bf(s.src[i + j]);
  *(bfx8*)(s.dst + i) = o;
}

// conv2_w (768,256,3,3) -> W2t [tap][o][c]
__global__ __launch_bounds__(256) void cvt_conv2w(const float* src, short* dst) {
  long idx = ((long)blockIdx.x * 256 + threadIdx.x) * 8;
  if (idx >= 9L * 768 * 256) return;
  int tap = (int)(idx / (768 * 256));
  int rem = (int)(idx % (768 * 256));
  int o = rem / 256;
  int c0 = rem % 256;
  bfx8 v;
  #pragma unroll
  for (int j = 0; j < 8; ++j) v[j] = f2bf(src[(long)o * 2304 + (long)(c0 + j) * 9 + tap]);
  *(bfx8*)(dst + idx) = v;
}

// fm [8][256][4096] f32 -> fmT [8][4096][256] bf16
__global__ __launch_bounds__(256) void transpose_fm(const float* fm, short* fmT) {
  __shared__ float tile[64][65];
  int p0 = blockIdx.x * 64, c0 = blockIdx.y * 64, b = blockIdx.z;
  int tp = threadIdx.x & 63, tr = threadIdx.x >> 6;
  const float* src = fm + ((long)b * 256 + c0) * 4096 + p0;
  #pragma unroll
  for (int i = 0; i < 16; ++i) {
    int c = tr + i * 4;
    tile[c][tp] = src[(long)c * 4096 + tp];
  }
  __syncthreads();
  short* dst = fmT + ((long)b * 4096 + p0) * 256 + c0;
  #pragma unroll
  for (int i = 0; i < 16; ++i) {
    int pp = tr + i * 4;
    dst[(long)pp * 256 + tp] = f2bf(tile[tp][pp]);
  }
}

// ---------------- 128x128 MFMA GEMM (m97 structure): OUT[m][n] = act(sum_k A[m][k]*B[n][k] + biases) ----------------
struct GemmP {
  const short* A; const short* B; void* O;
  const float* biasN; const float* biasM; const float* rowbias;
  long lda, ldb, ldo, sA, sB, sO;
  int M, N, K, outF32, act, padHW;
};

__global__ __launch_bounds__(256) void gemm128(GemmP g) {
  __shared__ short As[128 * 32];
  __shared__ short Bs[128 * 32];
  const int lane = threadIdx.x & 63, wv = threadIdx.x >> 6;
  const int wm = wv >> 1, wn = wv & 1;
  const int lg = lane >> 4, li = lane & 15;
  const int m0 = blockIdx.y * 128, n0 = blockIdx.x * 128, z = blockIdx.z;
  const short* A = g.A + (long)z * g.sA;
  const short* B = g.B + (long)z * g.sB;
  const int srow = wv * 16 + (lane >> 2);
  const int scol = (lane & 3) * 8;
  const short* pA0 = A + (long)(m0 + srow) * g.lda + scol;
  const short* pA1 = A + (long)(m0 + 64 + srow) * g.lda + scol;
  const short* pB0 = B + (long)(n0 + srow) * g.ldb + scol;
  const short* pB1 = B + (long)(n0 + 64 + srow) * g.ldb + scol;
  short* ldsA = As + wv * 512;
  short* ldsB = Bs + wv * 512;
  const short* aRd = As + (wm * 64 + li) * 32 + lg * 8;
  const short* bRd = Bs + (wn * 64 + li) * 32 + lg * 8;

  fx4 acc[4][4] = {};
  for (int kc = 0; kc < g.K; kc += 32) {
    gl_lds16(pA0 + kc, ldsA);
    gl_lds16(pA1 + kc, ldsA + 2048);
    gl_lds16(pB0 + kc, ldsB);
    gl_lds16(pB1 + kc, ldsB + 2048);
    __syncthreads();
    bfx8 af[4], bf[4];
    #pragma unroll
    for (int mi = 0; mi < 4; ++mi) af[mi] = *(const bfx8*)(aRd + mi * 16 * 32);
    #pragma unroll
    for (int ni = 0; ni < 4; ++ni) bf[ni] = *(const bfx8*)(bRd + ni * 16 * 32);
    #pragma unroll
    for (int mi = 0; mi < 4; ++mi)
      #pragma unroll
      for (int ni = 0; ni < 4; ++ni)
        MFMA16(acc[mi][ni], af[mi], bf[ni]);
    __syncthreads();
  }

  #pragma unroll
  for (int mi = 0; mi < 4; ++mi)
    #pragma unroll
    for (int ni = 0; ni < 4; ++ni) {
      int col = n0 + wn * 64 + ni * 16 + li;
      int rowb = m0 + wm * 64 + mi * 16 + 4 * lg;
      float bn = g.biasN ? g.biasN[col] : 0.0f;
      #pragma unroll
      for (int r = 0; r < 4; ++r) {
        int row = rowb + r;
        float v = acc[mi][ni][r] + bn;
        if (g.biasM) v += g.biasM[row];
        if (g.rowbias) v += g.rowbias[(long)(row >> 6) * g.N + col];
        if (g.act == 1) v = gelu_f(v);
        long orow = row;
        if (g.padHW) orow = (long)((row >> 6) + 1) * 66 + (row & 63) + 1;
        long oidx = (long)z * g.sO + orow * g.ldo + col;
        if (g.outF32) ((float*)g.O)[oidx] = v;
        else ((short*)g.O)[oidx] = f2bf(v);
      }
    }
}

// ---------------- conv2 3x3 implicit GEMM (m97 structure) + fused GN stats, XCD-swizzled ----------------
// xP: [8][66][66][256] bf16, zero border. W2t: [tap][768][256]. qkv: [8][4096][768].
__global__ __launch_bounds__(256) void conv2g(const short* xP, const short* W2t,
                                              const float* b2, short* qkv, float* stats) {
  __shared__ short As[128 * 32];
  __shared__ short Bs[128 * 32];
  __shared__ float red[4][4];
  const int lane = threadIdx.x & 63, wv = threadIdx.x >> 6;
  const int wm = wv >> 1, wn = wv & 1;
  const int lg = lane >> 4, li = lane & 15;
  // T1 XCD swizzle: 1536 blocks = 8 XCDs x 192; XCD x gets logical ids [x*192,(x+1)*192)
  const int w = ((int)blockIdx.x & 7) * 192 + ((int)blockIdx.x >> 3);
  const int n0 = (w % 6) * 128;
  const int by = w / 6;
  const int b = by >> 5, ypair = by & 31;
  const short* xPb = xP + (long)b * 66 * 66 * 256;

  const int srow = wv * 16 + (lane >> 2);
  const int scol = (lane & 3) * 8;
  long baseA[2], baseB[2];
  #pragma unroll
  for (int j = 0; j < 2; ++j) {
    int r = j * 64 + srow;
    int yy = 2 * ypair + (r >> 6);
    int x = r & 63;
    baseA[j] = ((long)yy * 66 + x) * 256 + scol;
    baseB[j] = (long)(n0 + r) * 256 + scol;
  }
  short* ldsA = As + wv * 512;
  short* ldsB = Bs + wv * 512;
  const short* aRd = As + (wm * 64 + li) * 32 + lg * 8;
  const short* bRd = Bs + (wn * 64 + li) * 32 + lg * 8;

  fx4 acc[4][4] = {};
  for (int ks = 0; ks < 72; ++ks) {
    int tap = ks >> 3;
    int c0 = (ks & 7) * 32;
    int dy = tap / 3, dx = tap - dy * 3;
    long aoff = (long)(dy * 66 + dx) * 256 + c0;
    long boff = (long)tap * (768 * 256) + c0;
    gl_lds16(xPb + baseA[0] + aoff, ldsA);
    gl_lds16(xPb + baseA[1] + aoff, ldsA + 2048);
    gl_lds16(W2t + baseB[0] + boff, ldsB);
    gl_lds16(W2t + baseB[1] + boff, ldsB + 2048);
    __syncthreads();
    bfx8 af[4], bf[4];
    #pragma unroll
    for (int mi = 0; mi < 4; ++mi) af[mi] = *(const bfx8*)(aRd + mi * 16 * 32);
    #pragma unroll
    for (int ni = 0; ni < 4; ++ni) bf[ni] = *(const bfx8*)(bRd + ni * 16 * 32);
    #pragma unroll
    for (int mi = 0; mi < 4; ++mi)
      #pragma unroll
      for (int ni = 0; ni < 4; ++ni)
        MFMA16(acc[mi][ni], af[mi], bf[ni]);
    __syncthreads();
  }

  // epilogue: bias, GN partial stats (group = col/192), store bf16
  const int g0 = n0 / 192;
  const int bnd = (g0 + 1) * 192;
  float sA = 0.0f, s2A = 0.0f, sB = 0.0f, s2B = 0.0f;
  const long prow0 = (long)b * 4096 + (long)ypair * 128 + wm * 64 + 4 * lg;
  #pragma unroll
  for (int ni = 0; ni < 4; ++ni) {
    int col = n0 + wn * 64 + ni * 16 + li;
    float bias = b2[col];
    bool inA = (col < bnd);
    #pragma unroll
    for (int mi = 0; mi < 4; ++mi) {
      long rb = prow0 + mi * 16;
      #pragma unroll
      for (int r = 0; r < 4; ++r) {
        float v = acc[mi][ni][r] + bias;
        if (inA) { sA += v; s2A += v * v; } else { sB += v; s2B += v * v; }
        qkv[(rb + r) * 768 + col] = f2bf(v);
      }
    }
  }
  #pragma unroll
  for (int off = 1; off < 64; off <<= 1) {
    sA += __shfl_xor(sA, off);  s2A += __shfl_xor(s2A, off);
    sB += __shfl_xor(sB, off);  s2B += __shfl_xor(s2B, off);
  }
  if (lane == 0) { red[wv][0] = sA; red[wv][1] = s2A; red[wv][2] = sB; red[wv][3] = s2B; }
  __syncthreads();
  if (threadIdx.x == 0) {
    float a1 = red[0][0] + red[1][0] + red[2][0] + red[3][0];
    float a2 = red[0][1] + red[1][1] + red[2][1] + red[3][1];
    atomicAdd(&stats[(b * 4 + g0) * 2], a1);
    atomicAdd(&stats[(b * 4 + g0) * 2 + 1], a2);
    if (bnd < n0 + 128) {
      float b1s = red[0][2] + red[1][2] + red[2][2] + red[3][2];
      float b2s = red[0][3] + red[1][3] + red[2][3] + red[3][3];
      atomicAdd(&stats[(b * 4 + g0 + 1) * 2], b1s);
      atomicAdd(&stats[(b * 4 + g0 + 1) * 2 + 1], b2s);
    }
  }
}

__global__ void gn_fin(const float* stats, float* mufs) {
  int i = threadIdx.x;
  if (i >= 32) return;
  float n = 192.0f * 4096.0f;
  float mu = stats[i * 2] / n;
  float var = stats[i * 2 + 1] / n - mu * mu;
  mufs[i * 2] = mu;
  mufs[i * 2 + 1] = rsqrtf(var + 1e-5f);
}

__global__ __launch_bounds__(256) void gn_norm(short* qkv, const float* mufs,
                                               const float* gnw, const float* gnb) {
  long base = ((long)blockIdx.x * 256 + threadIdx.x) * 8;
  int o = (int)(base % 768);
  int bg = (int)(base / (4096L * 768)) * 4 + o / 192;
  float mu = mufs[bg * 2], rs = mufs[bg * 2 + 1];
  bfx8 v = *(bfx8*)(qkv + base);
  bfx8 w;
  #pragma unroll
  for (int j = 0; j < 8; ++j) {
    float f = bf2f(v[j]);
    f = (f - mu) * rs * gnw[o + j] + gnb[o + j];
    w[j] = f2bf(f);
  }
  *(bfx8*)(qkv + base) = w;
}

// ---------------- local window attention: 1 block per (b,window), 1 head per wave ----------------
// qk: [32768][512] (q cols 0..255, k cols 256..511); vhT: [8][256][4096]
__global__ __launch_bounds__(256) void attn_local(const short* qk, const short* vhT, short* oat) {
  __shared__ short Pl[4 * 64 * 72];
  const int lane = threadIdx.x & 63, h = threadIdx.x >> 6;
  const int lg = lane >> 4, li = lane & 15;
  const int bw = blockIdx.x;
  const int b = bw >> 6, wY = bw & 63;
  const long p0 = (long)bw * 64;

  bfx8 qf[4][2], kf[4][2];
  #pragma unroll
  for (int mi = 0; mi < 4; ++mi)
    #pragma unroll
    for (int ks = 0; ks < 2; ++ks) {
      qf[mi][ks] = *(const bfx8*)(qk + (p0 + 16 * mi + li) * 512 + h * 64 + 32 * ks + 8 * lg);
      kf[mi][ks] = *(const bfx8*)(qk + (p0 + 16 * mi + li) * 512 + 256 + h * 64 + 32 * ks + 8 * lg);
    }
  fx4 s[4][4] = {};
  #pragma unroll
  for (int mi = 0; mi < 4; ++mi)
    #pragma unroll
    for (int ni = 0; ni < 4; ++ni) {
      MFMA16(s[mi][ni], qf[mi][0], kf[ni][0]);
      MFMA16(s[mi][ni], qf[mi][1], kf[ni][1]);
    }
  #pragma unroll
  for (int mi = 0; mi < 4; ++mi)
    #pragma unroll
    for (int ni = 0; ni < 4; ++ni) s[mi][ni] *= 0.125f;

  #pragma unroll
  for (int mi = 0; mi < 4; ++mi)
    #pragma unroll
    for (int r = 0; r < 4; ++r) {
      float mx = fmaxf(fmaxf(s[mi][0][r], s[mi][1][r]), fmaxf(s[mi][2][r], s[mi][3][r]));
      for (int off = 1; off < 16; off <<= 1) mx = fmaxf(mx, __shfl_xor(mx, off));
      float e[4];
      float sum = 0.0f;
      #pragma unroll
      for (int ni = 0; ni < 4; ++ni) { e[ni] = expf(s[mi][ni][r] - mx); sum += e[ni]; }
      for (int off = 1; off < 16; off <<= 1) sum += __shfl_xor(sum, off);
      float inv = 1.0f / sum;
      int row = h * 64 + 16 * mi + 4 * lg + r;
      #pragma unroll
      for (int ni = 0; ni < 4; ++ni) Pl[row * 72 + 16 * ni + li] = f2bf(e[ni] * inv);
    }
  __syncthreads();

  fx4 o[4][4] = {};
  #pragma unroll
  for (int ks = 0; ks < 2; ++ks) {
    bfx8 pf[4], vf[4];
    #pragma unroll
    for (int mi = 0; mi < 4; ++mi)
      pf[mi] = *(const bfx8*)(&Pl[(h * 64 + 16 * mi + li) * 72 + 32 * ks + 8 * lg]);
    #pragma unroll
    for (int ni = 0; ni < 4; ++ni)
      vf[ni] = *(const bfx8*)(vhT + ((long)(b * 256 + h * 64 + 16 * ni + li)) * 4096 + wY * 64 + 32 * ks + 8 * lg);
    #pragma unroll
    for (int mi = 0; mi < 4; ++mi)
      #pragma unroll
      for (int ni = 0; ni < 4; ++ni) MFMA16(o[mi][ni], pf[mi], vf[ni]);
  }
  #pragma unroll
  for (int mi = 0; mi < 4; ++mi)
    #pragma unroll
    for (int ni = 0; ni < 4; ++ni)
      #pragma unroll
      for (int r = 0; r < 4; ++r)
        oat[(p0 + 16 * mi + 4 * lg + r) * 256 + h * 64 + 16 * ni + li] = f2bf(o[mi][ni][r]);
}

// ---------------- small kernels ----------------
__global__ __launch_bounds__(256) void wmean(const short* loc, short* gq) {
  int bw = blockIdx.x, d = threadIdx.x;
  float s = 0.0f;
  for (int x = 0; x < 64; ++x) s += bf2f(loc[((long)bw * 64 + x) * 256 + d]);
  gq[(long)bw * 256 + d] = f2bf(s * (1.0f / 64.0f));
}

__global__ __launch_bounds__(256) void tfmean(const short* t, short* tf) {
  int bj = blockIdx.x, d = threadIdx.x;
  int b = bj >> 2, j = bj & 3;
  float s = 0.0f;
  for (int i = 0; i < 16; ++i) s += bf2f(t[((long)(b * 64 + j * 16 + i)) * 256 + d]);
  tf[(long)bj * 256 + d] = f2bf(s * (1.0f / 16.0f));
}

__global__ __launch_bounds__(256) void attn_glob(const short* tf, const short* Wqkv,
                                                 const float* inb, const short* qhg, short* og) {
  __shared__ float kh_s[4][256];
  __shared__ float vh_s[4][256];
  int b = blockIdx.x, t = threadIdx.x;
  {
    float ak[4], av[4];
    #pragma unroll
    for (int key = 0; key < 4; ++key) { ak[key] = inb[256 + t]; av[key] = inb[512 + t]; }
    const short* wk = Wqkv + (long)(256 + t) * 256;
    const short* wvp = Wqkv + (long)(512 + t) * 256;
    const short* tfb = tf + (long)b * 4 * 256;
    for (int d = 0; d < 256; ++d) {
      float wkd = bf2f(wk[d]), wvd = bf2f(wvp[d]);
      #pragma unroll
      for (int key = 0; key < 4; ++key) {
        float x = bf2f(tfb[key * 256 + d]);
        ak[key] += wkd * x;
        av[key] += wvd * x;
      }
    }
    #pragma unroll
    for (int key = 0; key < 4; ++key) { kh_s[key][t] = ak[key]; vh_s[key][t] = av[key]; }
  }
  __syncthreads();
  int wq = t >> 2, h = t & 3;
  const short* qrow = qhg + (long)(b * 64 + wq) * 256 + h * 64;
  float sc[4];
  #pragma unroll
  for (int key = 0; key < 4; ++key) {
    float s = 0.0f;
    for (int d = 0; d < 64; ++d) s += bf2f(qrow[d]) * kh_s[key][h * 64 + d];
    sc[key] = s * 0.125f;
  }
  float mx = fmaxf(fmaxf(sc[0], sc[1]), fmaxf(sc[2], sc[3]));
  float p[4], sum = 0.0f;
  #pragma unroll
  for (int key = 0; key < 4; ++key) { p[key] = expf(sc[key] - mx); sum += p[key]; }
  float inv = 1.0f / sum;
  #pragma unroll
  for (int key = 0; key < 4; ++key) p[key] *= inv;
  short* orow = og + (long)(b * 64 + wq) * 256 + h * 64;
  for (int d = 0; d < 64; ++d) {
    float o = p[0] * vh_s[0][h * 64 + d] + p[1] * vh_s[1][h * 64 + d] +
              p[2] * vh_s[2][h * 64 + d] + p[3] * vh_s[3][h * 64 + d];
    orow[d] = f2bf(o);
  }
}

__global__ __launch_bounds__(256) void ep2k(const short* hb, const short* w2, const float* b2, float* out) {
  int pp = blockIdx.x * 16 + (threadIdx.x >> 4);
  int e = threadIdx.x & 15;
  const short* hr = hb + (long)pp * 256;
  const short* wr = w2 + (long)e * 256;
  float acc = b2[e];
  for (int k = 0; k < 256; k += 8) {
    bfx8 hv = *(const bfx8*)(hr + k);
    bfx8 wv = *(const bfx8*)(wr + k);
    #pragma unroll
    for (int j = 0; j < 8; ++j) acc += bf2f(hv[j]) * bf2f(wv[j]);
  }
  out[(long)pp * 16 + e] = 1.0f / (1.0f + expf(-acc));
}

// ---------------- host ----------------
extern "C" void kernel_launch(void* const* d_in, const int* in_sizes, int n_in,
                              void* d_out, int out_size, void* d_ws, size_t ws_size,
                              hipStream_t stream) {
  (void)in_sizes; (void)n_in; (void)out_size; (void)ws_size;
  const float* fm  = (const float*)d_in[0];
  const float* txt = (const float*)d_in[1];
  const float* w1  = (const float*)d_in[2];
  const float* b1  = (const float*)d_in[3];
  const float* w2  = (const float*)d_in[4];
  const float* b2  = (const float*)d_in[5];
  const float* gnw = (const float*)d_in[6];
  const float* gnb = (const float*)d_in[7];
  const float* inw = (const float*)d_in[8];
  const float* inb = (const float*)d_in[9];
  const float* ow  = (const float*)d_in[10];
  const float* ob  = (const float*)d_in[11];
  const float* tw  = (const float*)d_in[12];
  const float* tb  = (const float*)d_in[13];
  const float* e1w = (const float*)d_in[14];
  const float* e1b = (const float*)d_in[15];
  const float* e2w = (const float*)d_in[16];
  const float* e2b = (const float*)d_in[17];
  float* out = (float*)d_out;

  char* base = (char*)d_ws;
  size_t off = 0;
  auto alloc = [&](size_t bytes) -> char* {
    char* r = base + off;
    off = (off + bytes + 255) & ~(size_t)255;
    return r;
  };
  short* W1bf = (short*)alloc(256 * 256 * 2);
  short* W2t  = (short*)alloc((size_t)9 * 768 * 256 * 2);
  short* Wqkv = (short*)alloc(768 * 256 * 2);
  short* Wo   = (short*)alloc(256 * 256 * 2);
  short* Wtxt = (short*)alloc(256 * 512 * 2);
  short* Wep1 = (short*)alloc(256 * 512 * 2);
  short* Wep2 = (short*)alloc(16 * 256 * 2);
  short* Tbf  = (short*)alloc((size_t)8 * 64 * 512 * 2);
  short* fmT  = (short*)alloc((size_t)8 * 4096 * 256 * 2);
  short* xP   = (short*)alloc((size_t)8 * 66 * 66 * 256 * 2);
  short* qkv  = (short*)alloc((size_t)8 * 4096 * 768 * 2);
  float* stats= (float*)alloc(64 * 4);
  float* mufs = (float*)alloc(64 * 4);
  short* qk   = (short*)alloc((size_t)32768 * 512 * 2);
  short* vhT  = (short*)alloc((size_t)8 * 4096 * 256 * 2);
  short* oat  = (short*)alloc((size_t)8 * 4096 * 256 * 2);
  short* loc  = (short*)alloc((size_t)8 * 4096 * 256 * 2);
  short* gq   = (short*)alloc(512 * 256 * 2);
  short* tm   = (short*)alloc(512 * 256 * 2);
  short* tfb  = (short*)alloc(32 * 256 * 2);
  short* qhg  = (short*)alloc(512 * 256 * 2);
  short* og   = (short*)alloc(512 * 256 * 2);
  short* glb  = (short*)alloc(512 * 256 * 2);
  float* gcon = (float*)alloc(512 * 256 * 4);
  short* hbuf = (short*)alloc((size_t)8 * 4096 * 256 * 2);

  hipMemsetAsync(stats, 0, 64 * 4, stream);
  hipMemsetAsync(xP, 0, (size_t)8 * 66 * 66 * 256 * 2, stream);

  CvtArgs ca;
  ca.s[0] = {w1,  W1bf, 256 * 256};
  ca.s[1] = {inw, Wqkv, 768 * 256};
  ca.s[2] = {ow,  Wo,   256 * 256};
  ca.s[3] = {tw,  Wtxt, 256 * 512};
  ca.s[4] = {e1w, Wep1, 256 * 512};
  ca.s[5] = {e2w, Wep2, 16 * 256};
  ca.s[6] = {txt, Tbf,  8 * 64 * 512};
  cvt_multi<<<dim3(128, 7), 256, 0, stream>>>(ca);
  cvt_conv2w<<<864, 256, 0, stream>>>(w2, W2t);
  transpose_fm<<<dim3(64, 4, 8), 256, 0, stream>>>(fm, fmT);

  { // conv1 1x1 + gelu -> xP (padded [66][66] layout)
    GemmP g{};
    g.A = fmT; g.lda = 256; g.sA = 4096L * 256;
    g.B = W1bf; g.ldb = 256; g.sB = 0;
    g.O = xP; g.ldo = 256; g.sO = 66L * 66 * 256;
    g.biasN = b1; g.M = 4096; g.N = 256; g.K = 256; g.act = 1; g.padHW = 1;
    gemm128<<<dim3(2, 32, 8), 256, 0, stream>>>(g);
  }

  conv2g<<<1536, 256, 0, stream>>>(xP, W2t, b2, qkv, stats);
  gn_fin<<<1, 32, 0, stream>>>(stats, mufs);
  gn_norm<<<12288, 256, 0, stream>>>(qkv, mufs, gnw, gnb);

  { // fused q+k projection: qk[32768][512]
    GemmP g{};
    g.A = qkv; g.lda = 768;
    g.B = Wqkv; g.ldb = 256;
    g.O = qk; g.ldo = 512;
    g.biasN = inb; g.M = 32768; g.N = 512; g.K = 256;
    gemm128<<<dim3(4, 256, 1), 256, 0, stream>>>(g);
  }
  { // proj v, transposed output vhT [b][dout][p]
    GemmP g{};
    g.A = Wqkv + 512 * 256; g.lda = 256; g.sA = 0;
    g.B = qkv + 512; g.ldb = 768; g.sB = 4096L * 768;
    g.O = vhT; g.ldo = 4096; g.sO = 256L * 4096;
    g.biasM = inb + 512; g.M = 256; g.N = 4096; g.K = 256;
    gemm128<<<dim3(32, 2, 8), 256, 0, stream>>>(g);
  }

  attn_local<<<512, 256, 0, stream>>>(qk, vhT, oat);

  { // out_proj -> loc
    GemmP g{};
    g.A = oat; g.lda = 256; g.B = Wo; g.ldb = 256;
    g.O = loc; g.ldo = 256; g.biasN = ob;
    g.M = 32768; g.N = 256; g.K = 256;
    gemm128<<<dim3(2, 256, 1), 256, 0, stream>>>(g);
  }

  wmean<<<512, 256, 0, stream>>>(loc, gq);

  { // text proj -> tm
    GemmP g{};
    g.A = Tbf; g.lda = 512; g.B = Wtxt; g.ldb = 512;
    g.O = tm; g.ldo = 256; g.biasN = tb;
    g.M = 512; g.N = 256; g.K = 512;
    gemm128<<<dim3(2, 4, 1), 256, 0, stream>>>(g);
  }
  tfmean<<<32, 256, 0, stream>>>(tm, tfb);

  { // global q projection
    GemmP g{};
    g.A = gq; g.lda = 256; g.B = Wqkv; g.ldb = 256;
    g.O = qhg; g.ldo = 256; g.biasN = inb;
    g.M = 512; g.N = 256; g.K = 256;
    gemm128<<<dim3(2, 4, 1), 256, 0, stream>>>(g);
  }

  attn_glob<<<8, 256, 0, stream>>>(tfb, Wqkv, inb, qhg, og);

  { // global out_proj -> glb
    GemmP g{};
    g.A = og; g.lda = 256; g.B = Wo; g.ldb = 256;
    g.O = glb; g.ldo = 256; g.biasN = ob;
    g.M = 512; g.N = 256; g.K = 256;
    gemm128<<<dim3(2, 4, 1), 256, 0, stream>>>(g);
  }
  { // gcontrib = glb @ ep1_w[:,256:].T + ep1_b  (f32)
    GemmP g{};
    g.A = glb; g.lda = 256; g.B = Wep1 + 256; g.ldb = 512;
    g.O = gcon; g.ldo = 256; g.biasN = e1b; g.outF32 = 1;
    g.M = 512; g.N = 256; g.K = 256;
    gemm128<<<dim3(2, 4, 1), 256, 0, stream>>>(g);
  }
  { // ep1: h = gelu(loc @ ep1_w[:,:256].T + gcontrib[row>>6])
    GemmP g{};
    g.A = loc; g.lda = 256; g.B = Wep1; g.ldb = 512;
    g.O = hbuf; g.ldo = 256; g.rowbias = gcon; g.act = 1;
    g.M = 32768; g.N = 256; g.K = 256;
    gemm128<<<dim3(2, 256, 1), 256, 0, stream>>>(g);
  }

  ep2k<<<2048, 256, 0, stream>>>(hbuf, Wep2, e2b, out);
}

// Round 4
// 460.534 us; speedup vs baseline: 2.4451x; 1.0035x over previous
//
#include <hip/hip_runtime.h>

#define DEV __device__ __forceinline__

typedef __attribute__((ext_vector_type(8))) short bfx8;
typedef __attribute__((ext_vector_type(4))) float fx4;

typedef __attribute__((address_space(3))) unsigned int as3_u32;
typedef const __attribute__((address_space(1))) unsigned int as1_u32c;

DEV void gl_lds16(const void* g, const void* l) {
  __builtin_amdgcn_global_load_lds((as1_u32c*)(unsigned long long)g,
                                   (as3_u32*)(unsigned long long)l, 16, 0, 0);
}

DEV short f2bf(float f) {
  unsigned u = __float_as_uint(f);
  u += 0x7fffu + ((u >> 16) & 1u);
  return (short)(u >> 16);
}
DEV float bf2f(short s) {
  return __uint_as_float(((unsigned)(unsigned short)s) << 16);
}
DEV float gelu_f(float x) { return 0.5f * x * (1.0f + erff(x * 0.70710678118654752f)); }

#define MFMA16(acc, a, b) (acc) = __builtin_amdgcn_mfma_f32_16x16x32_bf16((a), (b), (acc), 0, 0, 0)

// ---------------- conversions ----------------
struct CvtSeg { const float* src; short* dst; int n; };
struct CvtArgs { CvtSeg s[7]; };

__global__ __launch_bounds__(256) void cvt_multi(CvtArgs a) {
  CvtSeg s = a.s[blockIdx.y];
  int i = ((int)blockIdx.x * 256 + (int)threadIdx.x) * 8;
  if (i >= s.n) return;
  bfx8 o;
  #pragma unroll
  for (int j = 0; j < 8; ++j) o[j] = f2bf(s.src[i + j]);
  *(bfx8*)(s.dst + i) = o;
}

// conv2_w (768,256,3,3) -> W2t [tap][o][c]
__global__ __launch_bounds__(256) void cvt_conv2w(const float* src, short* dst) {
  long idx = ((long)blockIdx.x * 256 + threadIdx.x) * 8;
  if (idx >= 9L * 768 * 256) return;
  int tap = (int)(idx / (768 * 256));
  int rem = (int)(idx % (768 * 256));
  int o = rem / 256;
  int c0 = rem % 256;
  bfx8 v;
  #pragma unroll
  for (int j = 0; j < 8; ++j) v[j] = f2bf(src[(long)o * 2304 + (long)(c0 + j) * 9 + tap]);
  *(bfx8*)(dst + idx) = v;
}

// ---------------- fused transpose + conv1(1x1) + gelu ----------------
// fm [8][256][4096] f32 -> xP [8][66][66][256] bf16 (interior). One block = one image row (64 px).
// LDS layout: Af[p][c] f32, pitch 260 words, XOR-swizzled: word = p*260 + (c ^ (((p>>2)&7)<<2)).
DEV int axc(int p, int c) { return p * 260 + (c ^ (((p >> 2) & 7) << 2)); }

__global__ __launch_bounds__(256) void tc1(const float* fm, const short* W1bf,
                                           const float* b1, short* xP) {
  __shared__ float Af[64 * 260];
  const int lane = threadIdx.x & 63, wv = threadIdx.x >> 6;
  const int lg = lane >> 4, li = lane & 15;
  const int y = blockIdx.x & 63, b = blockIdx.x >> 6;
  const float* src = fm + (long)b * 256 * 4096 + y * 64;
  #pragma unroll
  for (int i = 0; i < 16; ++i) {
    int chunk = i * 256 + (int)threadIdx.x;  // 0..4095
    int c = chunk >> 4;                      // channel 0..255
    int q = chunk & 15;                      // 16B chunk within 64-px row
    fx4 v = *(const fx4*)(src + (long)c * 4096 + q * 4);
    #pragma unroll
    for (int j = 0; j < 4; ++j) Af[axc(q * 4 + j, c)] = v[j];
  }
  __syncthreads();

  fx4 acc[4][4] = {};
  const short* Bb = W1bf + (long)(wv * 64 + li) * 256 + lg * 8;
  for (int c0 = 0; c0 < 256; c0 += 32) {
    bfx8 af[4], bfr[4];
    #pragma unroll
    for (int mi = 0; mi < 4; ++mi) {
      int p = mi * 16 + li;
      fx4 lo = *(const fx4*)(&Af[axc(p, c0 + lg * 8)]);
      fx4 hi = *(const fx4*)(&Af[axc(p, c0 + lg * 8 + 4)]);
      bfx8 t;
      t[0] = f2bf(lo[0]); t[1] = f2bf(lo[1]); t[2] = f2bf(lo[2]); t[3] = f2bf(lo[3]);
      t[4] = f2bf(hi[0]); t[5] = f2bf(hi[1]); t[6] = f2bf(hi[2]); t[7] = f2bf(hi[3]);
      af[mi] = t;
    }
    #pragma unroll
    for (int ni = 0; ni < 4; ++ni) bfr[ni] = *(const bfx8*)(Bb + ni * 16 * 256 + c0);
    #pragma unroll
    for (int mi = 0; mi < 4; ++mi)
      #pragma unroll
      for (int ni = 0; ni < 4; ++ni) MFMA16(acc[mi][ni], af[mi], bfr[ni]);
  }

  short* dstP = xP + ((long)b * 66 * 66 + (long)(y + 1) * 66 + 1) * 256;
  #pragma unroll
  for (int mi = 0; mi < 4; ++mi)
    #pragma unroll
    for (int ni = 0; ni < 4; ++ni) {
      int col = wv * 64 + ni * 16 + li;
      float bias = b1[col];
      #pragma unroll
      for (int r = 0; r < 4; ++r) {
        int x = mi * 16 + 4 * lg + r;
        dstP[(long)x * 256 + col] = f2bf(gelu_f(acc[mi][ni][r] + bias));
      }
    }
}

// ---------------- 128x128 MFMA GEMM (m97 structure) ----------------
struct GemmP {
  const short* A; const short* B; void* O;
  const float* biasN; const float* biasM; const float* rowbias;
  long lda, ldb, ldo, sA, sB, sO;
  int M, N, K, outF32, act, padHW;
  int aShift;        // A column shift = (n0>>8)*aShift  (k-slice fix for fused qk)
  long sBN, sBM;     // per-z strides for biasN / biasM
};

__global__ __launch_bounds__(256) void gemm128(GemmP g) {
  __shared__ short As[128 * 32];
  __shared__ short Bs[128 * 32];
  const int lane = threadIdx.x & 63, wv = threadIdx.x >> 6;
  const int wm = wv >> 1, wn = wv & 1;
  const int lg = lane >> 4, li = lane & 15;
  const int m0 = blockIdx.y * 128, n0 = blockIdx.x * 128, z = blockIdx.z;
  const short* A = g.A + (long)z * g.sA + (long)(n0 >> 8) * g.aShift;
  const short* B = g.B + (long)z * g.sB;
  const int srow = wv * 16 + (lane >> 2);
  const int scol = (lane & 3) * 8;
  const short* pA0 = A + (long)(m0 + srow) * g.lda + scol;
  const short* pA1 = A + (long)(m0 + 64 + srow) * g.lda + scol;
  const short* pB0 = B + (long)(n0 + srow) * g.ldb + scol;
  const short* pB1 = B + (long)(n0 + 64 + srow) * g.ldb + scol;
  short* ldsA = As + wv * 512;
  short* ldsB = Bs + wv * 512;
  const short* aRd = As + (wm * 64 + li) * 32 + lg * 8;
  const short* bRd = Bs + (wn * 64 + li) * 32 + lg * 8;

  fx4 acc[4][4] = {};
  for (int kc = 0; kc < g.K; kc += 32) {
    gl_lds16(pA0 + kc, ldsA);
    gl_lds16(pA1 + kc, ldsA + 2048);
    gl_lds16(pB0 + kc, ldsB);
    gl_lds16(pB1 + kc, ldsB + 2048);
    __syncthreads();
    bfx8 af[4], bf[4];
    #pragma unroll
    for (int mi = 0; mi < 4; ++mi) af[mi] = *(const bfx8*)(aRd + mi * 16 * 32);
    #pragma unroll
    for (int ni = 0; ni < 4; ++ni) bf[ni] = *(const bfx8*)(bRd + ni * 16 * 32);
    #pragma unroll
    for (int mi = 0; mi < 4; ++mi)
      #pragma unroll
      for (int ni = 0; ni < 4; ++ni)
        MFMA16(acc[mi][ni], af[mi], bf[ni]);
    __syncthreads();
  }

  #pragma unroll
  for (int mi = 0; mi < 4; ++mi)
    #pragma unroll
    for (int ni = 0; ni < 4; ++ni) {
      int col = n0 + wn * 64 + ni * 16 + li;
      int rowb = m0 + wm * 64 + mi * 16 + 4 * lg;
      float bn = g.biasN ? g.biasN[(long)z * g.sBN + col] : 0.0f;
      #pragma unroll
      for (int r = 0; r < 4; ++r) {
        int row = rowb + r;
        float v = acc[mi][ni][r] + bn;
        if (g.biasM) v += g.biasM[(long)z * g.sBM + row];
        if (g.rowbias) v += g.rowbias[(long)(row >> 6) * g.N + col];
        if (g.act == 1) v = gelu_f(v);
        long orow = row;
        if (g.padHW) orow = (long)((row >> 6) + 1) * 66 + (row & 63) + 1;
        long oidx = (long)z * g.sO + orow * g.ldo + col;
        if (g.outF32) ((float*)g.O)[oidx] = v;
        else ((short*)g.O)[oidx] = f2bf(v);
      }
    }
}

// ---------------- conv2 3x3 implicit GEMM (m97 structure) + fused GN stats, XCD-swizzled ----------------
__global__ __launch_bounds__(256) void conv2g(const short* xP, const short* W2t,
                                              const float* b2, short* qkv, float* stats) {
  __shared__ short As[128 * 32];
  __shared__ short Bs[128 * 32];
  __shared__ float red[4][4];
  const int lane = threadIdx.x & 63, wv = threadIdx.x >> 6;
  const int wm = wv >> 1, wn = wv & 1;
  const int lg = lane >> 4, li = lane & 15;
  const int w = ((int)blockIdx.x & 7) * 192 + ((int)blockIdx.x >> 3);
  const int n0 = (w % 6) * 128;
  const int by = w / 6;
  const int b = by >> 5, ypair = by & 31;
  const short* xPb = xP + (long)b * 66 * 66 * 256;

  const int srow = wv * 16 + (lane >> 2);
  const int scol = (lane & 3) * 8;
  long baseA[2], baseB[2];
  #pragma unroll
  for (int j = 0; j < 2; ++j) {
    int r = j * 64 + srow;
    int yy = 2 * ypair + (r >> 6);
    int x = r & 63;
    baseA[j] = ((long)yy * 66 + x) * 256 + scol;
    baseB[j] = (long)(n0 + r) * 256 + scol;
  }
  short* ldsA = As + wv * 512;
  short* ldsB = Bs + wv * 512;
  const short* aRd = As + (wm * 64 + li) * 32 + lg * 8;
  const short* bRd = Bs + (wn * 64 + li) * 32 + lg * 8;

  fx4 acc[4][4] = {};
  #pragma unroll
  for (int dy = 0; dy < 3; ++dy)
    #pragma unroll
    for (int dx = 0; dx < 3; ++dx) {
      const short* aT = xPb + (dy * 66 + dx) * 256;
      const short* bT = W2t + (long)(dy * 3 + dx) * (768 * 256);
      for (int c0 = 0; c0 < 256; c0 += 32) {
        gl_lds16(aT + baseA[0] + c0, ldsA);
        gl_lds16(aT + baseA[1] + c0, ldsA + 2048);
        gl_lds16(bT + baseB[0] + c0, ldsB);
        gl_lds16(bT + baseB[1] + c0, ldsB + 2048);
        __syncthreads();
        bfx8 af[4], bf[4];
        #pragma unroll
        for (int mi = 0; mi < 4; ++mi) af[mi] = *(const bfx8*)(aRd + mi * 16 * 32);
        #pragma unroll
        for (int ni = 0; ni < 4; ++ni) bf[ni] = *(const bfx8*)(bRd + ni * 16 * 32);
        #pragma unroll
        for (int mi = 0; mi < 4; ++mi)
          #pragma unroll
          for (int ni = 0; ni < 4; ++ni)
            MFMA16(acc[mi][ni], af[mi], bf[ni]);
        __syncthreads();
      }
    }

  // epilogue: bias, GN partial stats (group = col/192), store raw bf16
  const int g0 = n0 / 192;
  const int bnd = (g0 + 1) * 192;
  float sA = 0.0f, s2A = 0.0f, sB = 0.0f, s2B = 0.0f;
  const long prow0 = (long)b * 4096 + (long)ypair * 128 + wm * 64 + 4 * lg;
  #pragma unroll
  for (int ni = 0; ni < 4; ++ni) {
    int col = n0 + wn * 64 + ni * 16 + li;
    float bias = b2[col];
    bool inA = (col < bnd);
    #pragma unroll
    for (int mi = 0; mi < 4; ++mi) {
      long rb = prow0 + mi * 16;
      #pragma unroll
      for (int r = 0; r < 4; ++r) {
        float v = acc[mi][ni][r] + bias;
        if (inA) { sA += v; s2A += v * v; } else { sB += v; s2B += v * v; }
        qkv[(rb + r) * 768 + col] = f2bf(v);
      }
    }
  }
  #pragma unroll
  for (int off = 1; off < 64; off <<= 1) {
    sA += __shfl_xor(sA, off);  s2A += __shfl_xor(s2A, off);
    sB += __shfl_xor(sB, off);  s2B += __shfl_xor(s2B, off);
  }
  if (lane == 0) { red[wv][0] = sA; red[wv][1] = s2A; red[wv][2] = sB; red[wv][3] = s2B; }
  __syncthreads();
  if (threadIdx.x == 0) {
    float a1 = red[0][0] + red[1][0] + red[2][0] + red[3][0];
    float a2 = red[0][1] + red[1][1] + red[2][1] + red[3][1];
    atomicAdd(&stats[(b * 4 + g0) * 2], a1);
    atomicAdd(&stats[(b * 4 + g0) * 2 + 1], a2);
    if (bnd < n0 + 128) {
      float b1s = red[0][2] + red[1][2] + red[2][2] + red[3][2];
      float b2s = red[0][3] + red[1][3] + red[2][3] + red[3][3];
      atomicAdd(&stats[(b * 4 + g0 + 1) * 2], b1s);
      atomicAdd(&stats[(b * 4 + g0 + 1) * 2 + 1], b2s);
    }
  }
}

__global__ void gn_fin(const float* stats, float* mufs) {
  int i = threadIdx.x;
  if (i >= 32) return;
  float n = 192.0f * 4096.0f;
  float mu = stats[i * 2] / n;
  float var = stats[i * 2 + 1] / n - mu * mu;
  mufs[i * 2] = mu;
  mufs[i * 2 + 1] = rsqrtf(var + 1e-5f);
}

// fold GN affine into per-batch projection weights:
// Wf[b][j][c] = inw[j][c] * s[b][cg],  bfold[b][j] = inb[j] + sum_c t[b][cg]*inw[j][c]
// cg = (j>>8)*256 + c;  s = rs*gnw[cg];  t = gnb[cg] - mu*s
__global__ __launch_bounds__(256) void gn_fold(const float* mufs, const float* gnw, const float* gnb,
                                               const float* inw, const float* inb,
                                               short* Wf, float* bfold) {
  const int lane = threadIdx.x & 63, wv = threadIdx.x >> 6;
  const int row = blockIdx.x * 4 + wv;   // 0..6143
  const int b = row / 768, j = row - b * 768;
  const int cb = (j >> 8) << 8;
  float part = 0.0f;
  #pragma unroll
  for (int i = 0; i < 4; ++i) {
    int c = lane + 64 * i;
    int cg = cb + c;
    int grp = cg / 192;
    float mu = mufs[(b * 4 + grp) * 2];
    float rs = mufs[(b * 4 + grp) * 2 + 1];
    float s = rs * gnw[cg];
    float t = gnb[cg] - mu * s;
    float wv_ = inw[(long)j * 256 + c];
    Wf[(long)row * 256 + c] = f2bf(wv_ * s);
    part += t * wv_;
  }
  #pragma unroll
  for (int off = 1; off < 64; off <<= 1) part += __shfl_xor(part, off);
  if (lane == 0) bfold[row] = inb[j] + part;
}

// ---------------- local window attention ----------------
__global__ __launch_bounds__(256) void attn_local(const short* qk, const short* vhT, short* oat) {
  __shared__ short Pl[4 * 64 * 72];
  const int lane = threadIdx.x & 63, h = threadIdx.x >> 6;
  const int lg = lane >> 4, li = lane & 15;
  const int bw = blockIdx.x;
  const int b = bw >> 6, wY = bw & 63;
  const long p0 = (long)bw * 64;

  bfx8 qf[4][2], kf[4][2];
  #pragma unroll
  for (int mi = 0; mi < 4; ++mi)
    #pragma unroll
    for (int ks = 0; ks < 2; ++ks) {
      qf[mi][ks] = *(const bfx8*)(qk + (p0 + 16 * mi + li) * 512 + h * 64 + 32 * ks + 8 * lg);
      kf[mi][ks] = *(const bfx8*)(qk + (p0 + 16 * mi + li) * 512 + 256 + h * 64 + 32 * ks + 8 * lg);
    }
  fx4 s[4][4] = {};
  #pragma unroll
  for (int mi = 0; mi < 4; ++mi)
    #pragma unroll
    for (int ni = 0; ni < 4; ++ni) {
      MFMA16(s[mi][ni], qf[mi][0], kf[ni][0]);
      MFMA16(s[mi][ni], qf[mi][1], kf[ni][1]);
    }
  #pragma unroll
  for (int mi = 0; mi < 4; ++mi)
    #pragma unroll
    for (int ni = 0; ni < 4; ++ni) s[mi][ni] *= 0.125f;

  #pragma unroll
  for (int mi = 0; mi < 4; ++mi)
    #pragma unroll
    for (int r = 0; r < 4; ++r) {
      float mx = fmaxf(fmaxf(s[mi][0][r], s[mi][1][r]), fmaxf(s[mi][2][r], s[mi][3][r]));
      for (int off = 1; off < 16; off <<= 1) mx = fmaxf(mx, __shfl_xor(mx, off));
      float e[4];
      float sum = 0.0f;
      #pragma unroll
      for (int ni = 0; ni < 4; ++ni) { e[ni] = expf(s[mi][ni][r] - mx); sum += e[ni]; }
      for (int off = 1; off < 16; off <<= 1) sum += __shfl_xor(sum, off);
      float inv = 1.0f / sum;
      int row = h * 64 + 16 * mi + 4 * lg + r;
      #pragma unroll
      for (int ni = 0; ni < 4; ++ni) Pl[row * 72 + 16 * ni + li] = f2bf(e[ni] * inv);
    }
  __syncthreads();

  fx4 o[4][4] = {};
  #pragma unroll
  for (int ks = 0; ks < 2; ++ks) {
    bfx8 pf[4], vf[4];
    #pragma unroll
    for (int mi = 0; mi < 4; ++mi)
      pf[mi] = *(const bfx8*)(&Pl[(h * 64 + 16 * mi + li) * 72 + 32 * ks + 8 * lg]);
    #pragma unroll
    for (int ni = 0; ni < 4; ++ni)
      vf[ni] = *(const bfx8*)(vhT + ((long)(b * 256 + h * 64 + 16 * ni + li)) * 4096 + wY * 64 + 32 * ks + 8 * lg);
    #pragma unroll
    for (int mi = 0; mi < 4; ++mi)
      #pragma unroll
      for (int ni = 0; ni < 4; ++ni) MFMA16(o[mi][ni], pf[mi], vf[ni]);
  }
  #pragma unroll
  for (int mi = 0; mi < 4; ++mi)
    #pragma unroll
    for (int ni = 0; ni < 4; ++ni)
      #pragma unroll
      for (int r = 0; r < 4; ++r)
        oat[(p0 + 16 * mi + 4 * lg + r) * 256 + h * 64 + 16 * ni + li] = f2bf(o[mi][ni][r]);
}

// ---------------- small kernels ----------------
__global__ __launch_bounds__(256) void wmean(const short* loc, short* gq) {
  int bw = blockIdx.x, d = threadIdx.x;
  float s = 0.0f;
  for (int x = 0; x < 64; ++x) s += bf2f(loc[((long)bw * 64 + x) * 256 + d]);
  gq[(long)bw * 256 + d] = f2bf(s * (1.0f / 64.0f));
}

__global__ __launch_bounds__(256) void tfmean(const short* t, short* tf) {
  int bj = blockIdx.x, d = threadIdx.x;
  int b = bj >> 2, j = bj & 3;
  float s = 0.0f;
  for (int i = 0; i < 16; ++i) s += bf2f(t[((long)(b * 64 + j * 16 + i)) * 256 + d]);
  tf[(long)bj * 256 + d] = f2bf(s * (1.0f / 16.0f));
}

__global__ __launch_bounds__(256) void attn_glob(const short* tf, const short* Wqkv,
                                                 const float* inb, const short* qhg, short* og) {
  __shared__ float kh_s[4][256];
  __shared__ float vh_s[4][256];
  int b = blockIdx.x, t = threadIdx.x;
  {
    float ak[4], av[4];
    #pragma unroll
    for (int key = 0; key < 4; ++key) { ak[key] = inb[256 + t]; av[key] = inb[512 + t]; }
    const short* wk = Wqkv + (long)(256 + t) * 256;
    const short* wvp = Wqkv + (long)(512 + t) * 256;
    const short* tfb = tf + (long)b * 4 * 256;
    for (int d = 0; d < 256; ++d) {
      float wkd = bf2f(wk[d]), wvd = bf2f(wvp[d]);
      #pragma unroll
      for (int key = 0; key < 4; ++key) {
        float x = bf2f(tfb[key * 256 + d]);
        ak[key] += wkd * x;
        av[key] += wvd * x;
      }
    }
    #pragma unroll
    for (int key = 0; key < 4; ++key) { kh_s[key][t] = ak[key]; vh_s[key][t] = av[key]; }
  }
  __syncthreads();
  int wq = t >> 2, h = t & 3;
  const short* qrow = qhg + (long)(b * 64 + wq) * 256 + h * 64;
  float sc[4];
  #pragma unroll
  for (int key = 0; key < 4; ++key) {
    float s = 0.0f;
    for (int d = 0; d < 64; ++d) s += bf2f(qrow[d]) * kh_s[key][h * 64 + d];
    sc[key] = s * 0.125f;
  }
  float mx = fmaxf(fmaxf(sc[0], sc[1]), fmaxf(sc[2], sc[3]));
  float p[4], sum = 0.0f;
  #pragma unroll
  for (int key = 0; key < 4; ++key) { p[key] = expf(sc[key] - mx); sum += p[key]; }
  float inv = 1.0f / sum;
  #pragma unroll
  for (int key = 0; key < 4; ++key) p[key] *= inv;
  short* orow = og + (long)(b * 64 + wq) * 256 + h * 64;
  for (int d = 0; d < 64; ++d) {
    float o = p[0] * vh_s[0][h * 64 + d] + p[1] * vh_s[1][h * 64 + d] +
              p[2] * vh_s[2][h * 64 + d] + p[3] * vh_s[3][h * 64 + d];
    orow[d] = f2bf(o);
  }
}

__global__ __launch_bounds__(256) void ep2k(const short* hb, const short* w2, const float* b2, float* out) {
  int pp = blockIdx.x * 16 + (threadIdx.x >> 4);
  int e = threadIdx.x & 15;
  const short* hr = hb + (long)pp * 256;
  const short* wr = w2 + (long)e * 256;
  float acc = b2[e];
  for (int k = 0; k < 256; k += 8) {
    bfx8 hv = *(const bfx8*)(hr + k);
    bfx8 wv = *(const bfx8*)(wr + k);
    #pragma unroll
    for (int j = 0; j < 8; ++j) acc += bf2f(hv[j]) * bf2f(wv[j]);
  }
  out[(long)pp * 16 + e] = 1.0f / (1.0f + expf(-acc));
}

// ---------------- host ----------------
extern "C" void kernel_launch(void* const* d_in, const int* in_sizes, int n_in,
                              void* d_out, int out_size, void* d_ws, size_t ws_size,
                              hipStream_t stream) {
  (void)in_sizes; (void)n_in; (void)out_size; (void)ws_size;
  const float* fm  = (const float*)d_in[0];
  const float* txt = (const float*)d_in[1];
  const float* w1  = (const float*)d_in[2];
  const float* b1  = (const float*)d_in[3];
  const float* w2  = (const float*)d_in[4];
  const float* b2  = (const float*)d_in[5];
  const float* gnw = (const float*)d_in[6];
  const float* gnb = (const float*)d_in[7];
  const float* inw = (const float*)d_in[8];
  const float* inb = (const float*)d_in[9];
  const float* ow  = (const float*)d_in[10];
  const float* ob  = (const float*)d_in[11];
  const float* tw  = (const float*)d_in[12];
  const float* tb  = (const float*)d_in[13];
  const float* e1w = (const float*)d_in[14];
  const float* e1b = (const float*)d_in[15];
  const float* e2w = (const float*)d_in[16];
  const float* e2b = (const float*)d_in[17];
  float* out = (float*)d_out;

  char* base = (char*)d_ws;
  size_t off = 0;
  auto alloc = [&](size_t bytes) -> char* {
    char* r = base + off;
    off = (off + bytes + 255) & ~(size_t)255;
    return r;
  };
  short* W1bf = (short*)alloc(256 * 256 * 2);
  short* W2t  = (short*)alloc((size_t)9 * 768 * 256 * 2);
  short* Wqkv = (short*)alloc(768 * 256 * 2);
  short* Wo   = (short*)alloc(256 * 256 * 2);
  short* Wtxt = (short*)alloc(256 * 512 * 2);
  short* Wep1 = (short*)alloc(256 * 512 * 2);
  short* Wep2 = (short*)alloc(16 * 256 * 2);
  short* Tbf  = (short*)alloc((size_t)8 * 64 * 512 * 2);
  short* xP   = (short*)alloc((size_t)8 * 66 * 66 * 256 * 2);
  short* qkv  = (short*)alloc((size_t)8 * 4096 * 768 * 2);
  float* stats= (float*)alloc(64 * 4);
  float* mufs = (float*)alloc(64 * 4);
  short* Wf   = (short*)alloc((size_t)8 * 768 * 256 * 2);
  float* bfold= (float*)alloc((size_t)8 * 768 * 4);
  short* qk   = (short*)alloc((size_t)32768 * 512 * 2);
  short* vhT  = (short*)alloc((size_t)8 * 4096 * 256 * 2);
  short* oat  = (short*)alloc((size_t)8 * 4096 * 256 * 2);
  short* loc  = (short*)alloc((size_t)8 * 4096 * 256 * 2);
  short* gq   = (short*)alloc(512 * 256 * 2);
  short* tm   = (short*)alloc(512 * 256 * 2);
  short* tfb  = (short*)alloc(32 * 256 * 2);
  short* qhg  = (short*)alloc(512 * 256 * 2);
  short* og   = (short*)alloc(512 * 256 * 2);
  short* glb  = (short*)alloc(512 * 256 * 2);
  float* gcon = (float*)alloc(512 * 256 * 4);
  short* hbuf = (short*)alloc((size_t)8 * 4096 * 256 * 2);

  hipMemsetAsync(stats, 0, 64 * 4, stream);
  hipMemsetAsync(xP, 0, (size_t)8 * 66 * 66 * 256 * 2, stream);

  CvtArgs ca;
  ca.s[0] = {w1,  W1bf, 256 * 256};
  ca.s[1] = {inw, Wqkv, 768 * 256};
  ca.s[2] = {ow,  Wo,   256 * 256};
  ca.s[3] = {tw,  Wtxt, 256 * 512};
  ca.s[4] = {e1w, Wep1, 256 * 512};
  ca.s[5] = {e2w, Wep2, 16 * 256};
  ca.s[6] = {txt, Tbf,  8 * 64 * 512};
  cvt_multi<<<dim3(128, 7), 256, 0, stream>>>(ca);
  cvt_conv2w<<<864, 256, 0, stream>>>(w2, W2t);

  tc1<<<512, 256, 0, stream>>>(fm, W1bf, b1, xP);

  conv2g<<<1536, 256, 0, stream>>>(xP, W2t, b2, qkv, stats);
  gn_fin<<<1, 32, 0, stream>>>(stats, mufs);
  gn_fold<<<1536, 256, 0, stream>>>(mufs, gnw, gnb, inw, inb, Wf, bfold);

  { // fused q+k projection with GN fold + per-block A slice: qk[32768][512]
    GemmP g{};
    g.A = qkv; g.lda = 768; g.sA = 4096L * 768;
    g.B = Wf; g.ldb = 256; g.sB = 768L * 256;
    g.O = qk; g.ldo = 512; g.sO = 4096L * 512;
    g.biasN = bfold; g.sBN = 768;
    g.aShift = 256;
    g.M = 4096; g.N = 512; g.K = 256;
    gemm128<<<dim3(4, 32, 8), 256, 0, stream>>>(g);
  }
  { // proj v (GN-folded), transposed output vhT [b][dout][p]
    GemmP g{};
    g.A = Wf + 512 * 256; g.lda = 256; g.sA = 768L * 256;
    g.B = qkv + 512; g.ldb = 768; g.sB = 4096L * 768;
    g.O = vhT; g.ldo = 4096; g.sO = 256L * 4096;
    g.biasM = bfold + 512; g.sBM = 768;
    g.M = 256; g.N = 4096; g.K = 256;
    gemm128<<<dim3(32, 2, 8), 256, 0, stream>>>(g);
  }

  attn_local<<<512, 256, 0, stream>>>(qk, vhT, oat);

  { // out_proj -> loc
    GemmP g{};
    g.A = oat; g.lda = 256; g.B = Wo; g.ldb = 256;
    g.O = loc; g.ldo = 256; g.biasN = ob;
    g.M = 32768; g.N = 256; g.K = 256;
    gemm128<<<dim3(2, 256, 1), 256, 0, stream>>>(g);
  }

  wmean<<<512, 256, 0, stream>>>(loc, gq);

  { // text proj -> tm
    GemmP g{};
    g.A = Tbf; g.lda = 512; g.B = Wtxt; g.ldb = 512;
    g.O = tm; g.ldo = 256; g.biasN = tb;
    g.M = 512; g.N = 256; g.K = 512;
    gemm128<<<dim3(2, 4, 1), 256, 0, stream>>>(g);
  }
  tfmean<<<32, 256, 0, stream>>>(tm, tfb);

  { // global q projection (raw weights, no GN)
    GemmP g{};
    g.A = gq; g.lda = 256; g.B = Wqkv; g.ldb = 256;
    g.O = qhg; g.ldo = 256; g.biasN = inb;
    g.M = 512; g.N = 256; g.K = 256;
    gemm128<<<dim3(2, 4, 1), 256, 0, stream>>>(g);
  }

  attn_glob<<<8, 256, 0, stream>>>(tfb, Wqkv, inb, qhg, og);

  { // global out_proj -> glb
    GemmP g{};
    g.A = og; g.lda = 256; g.B = Wo; g.ldb = 256;
    g.O = glb; g.ldo = 256; g.biasN = ob;
    g.M = 512; g.N = 256; g.K = 256;
    gemm128<<<dim3(2, 4, 1), 256, 0, stream>>>(g);
  }
  { // gcontrib = glb @ ep1_w[:,256:].T + ep1_b  (f32)
    GemmP g{};
    g.A = glb; g.lda = 256; g.B = Wep1 + 256; g.ldb = 512;
    g.O = gcon; g.ldo = 256; g.biasN = e1b; g.outF32 = 1;
    g.M = 512; g.N = 256; g.K = 256;
    gemm128<<<dim3(2, 4, 1), 256, 0, stream>>>(g);
  }
  { // ep1: h = gelu(loc @ ep1_w[:,:256].T + gcontrib[row>>6])
    GemmP g{};
    g.A = loc; g.lda = 256; g.B = Wep1; g.ldb = 512;
    g.O = hbuf; g.ldo = 256; g.rowbias = gcon; g.act = 1;
    g.M = 32768; g.N = 256; g.K = 256;
    gemm128<<<dim3(2, 256, 1), 256, 0, stream>>>(g);
  }

  ep2k<<<2048, 256, 0, stream>>>(hbuf, Wep2, e2b, out);
}